// Round 26
// baseline (646.211 us; speedup 1.0000x reference)
//
#include <hip/hip_runtime.h>

#define NHW 1024
#define NB 4
#define DM 256
#define NTOK 4096      // NHW * NB
#define NCIN 272
#define NDFF 1024

typedef unsigned short u16;
typedef unsigned int u32;
typedef __attribute__((ext_vector_type(8))) short s16x8;
typedef __attribute__((ext_vector_type(4))) float f32x4;

static const int GEMM_SMEM32 = (32+32+64+64)*56*2;   // 21504 B (BK=32)
static const int GEMM_SMEM64 = (32+32+64+64)*72*2;   // 27648 B (BK=64)

__device__ __forceinline__ float4 ld4(const float* p){ return *(const float4*)p; }
__device__ __forceinline__ void st4(float* p, float4 v){ *(float4*)p = v; }

// split fp32 -> bf16 hi + bf16 lo  (hi = RNE(x); lo = RNE(x - hi))
__device__ __forceinline__ void splitf(float x, u16& h, u16& l){
  u32 u = __float_as_uint(x);
  u32 hu = (u + (0x7FFFu + ((u >> 16) & 1u))) >> 16;
  h = (u16)hu;
  float hf = __uint_as_float(hu << 16);
  float r = x - hf;
  u32 v = __float_as_uint(r);
  v += 0x7FFFu + ((v >> 16) & 1u);
  l = (u16)(v >> 16);
}

__device__ __forceinline__ u32 packf(float x){
  u16 h,l; splitf(x,h,l);
  return (u32)h | ((u32)l << 16);
}

// ---------------- positional embedding ----------------
__global__ void pos_kernel(float* __restrict__ pos){
  int s = blockIdx.x, d = threadIdx.x;
  int row = s >> 5, col = s & 31;
  float base = (d < 128) ? (float)(row + 1) : (float)(col + 1);
  float val = base / (32.0f + 1e-6f) * 6.2831853071795864f;
  int dd = (d < 128) ? d : d - 128;
  int mf = dd >> 1;
  float f = powf(10000.0f, (float)mf * (1.0f/64.0f));
  float a = val / f;
  pos[s*DM + d] = (dd & 1) ? cosf(a) : sinf(a);
}

// ---------------- transposes ----------------
__global__ void tin_kernel(const float* __restrict__ x, float* __restrict__ tok){
  int idx = blockIdx.x*256 + threadIdx.x;
  if (idx >= NTOK*NCIN) return;
  int c = idx % NCIN;
  int n = idx / NCIN;
  int s = n >> 2, b = n & 3;
  tok[idx] = x[((long)(b*NCIN + c))*NHW + s];
}
__global__ void tout_kernel(const float* __restrict__ rec, float* __restrict__ out){
  int idx = blockIdx.x*256 + threadIdx.x;
  if (idx >= NTOK*NCIN) return;
  int s = idx & (NHW-1);
  int bc = idx >> 10;
  int b = bc / NCIN, c = bc % NCIN;
  out[idx] = rec[((long)(s*NB + b))*NCIN + c];
}

// -------- weight transpose+split: in [K][N] fp32 -> hi/lo planes [N][K] bf16 --------
__global__ __launch_bounds__(256) void tconv_kernel(const float* __restrict__ in,
    u16* __restrict__ oh, u16* __restrict__ ol, int K, int N){
  __shared__ float tile[32][33];
  long base = (long)blockIdx.z * (long)K * (long)N;
  int k0 = blockIdx.y*32, n0 = blockIdx.x*32;
  int tx = threadIdx.x & 31, ty = threadIdx.x >> 5;   // ty 0..7
  #pragma unroll
  for (int i=0;i<32;i+=8)
    tile[ty+i][tx] = in[base + (long)(k0+ty+i)*N + n0+tx];
  __syncthreads();
  #pragma unroll
  for (int i=0;i<32;i+=8){
    float v = tile[tx][ty+i];
    u16 h,l; splitf(v,h,l);
    long o = base + (long)(n0+ty+i)*K + k0+tx;
    oh[o]=h; ol[o]=l;
  }
}

// -------- elementwise split (no transpose): [N][K] fp32 -> hi/lo planes --------
__global__ void wsplit_kernel(const float* __restrict__ in, u16* __restrict__ oh,
    u16* __restrict__ ol, int n){
  int i = blockIdx.x*256 + threadIdx.x;
  if (i < n){ u16 h,l; splitf(in[i],h,l); oh[i]=h; ol[i]=l; }
}

// ---------------- split-bf16 MFMA GEMM body (3-term, DEPTH-2 reg-prefetch) ----------------
// Two static register stage-sets S0/S1; load for tile t+2 is issued during tile t's
// compute phase -> ~2 compute phases of latency coverage. Values/order bitwise-identical.
// ASRC 0: A fp32. 1: A packed hi|lo u32. 2: A fp32 + pos[n>>2]. 3: A fp32 s-indexed + pos.
// ASRC 5: A = split-KV attention partials (O0+O1)*1/(l0+l1) fused merge; Av=OpB, pos=lB.
// CDST 0: C fp32. 1: C packed u32 pairs. 2: C fp32 scattered to row jmap[r], scaled by sflat.
template<bool GROUPED, bool INDIRECT, int ASRC, bool RELU, int CDST, int BK>
__device__ __forceinline__ void sgemm_body(
    const void* __restrict__ Av, int lda,
    const float* __restrict__ pos,
    const u16* __restrict__ Bhp, const u16* __restrict__ Blp, int ldb,
    const float* __restrict__ bias,
    void* __restrict__ Cv, int ldc,
    int M, int N, int K,
    const int* __restrict__ map,
    const int* __restrict__ cnt,
    const int* __restrict__ offs,
    const int* __restrict__ jmap,
    const float* __restrict__ sflat,
    long strideB, int strideBias, int e)
{
  constexpr int BM = 32;
  constexpr int NSEG = BK/32;
  constexpr int SW = (BK==32) ? 56 : 72;   // LDS row stride in u16 (16B aligned)
  int rows = GROUPED ? cnt[e] : M;
  int bn = blockIdx.x, bm = blockIdx.y;    // bn fastest: A-sharing blocks adjacent (L2)
  if (bm*BM >= rows) return;
  int row0 = GROUPED ? offs[e] : 0;
  const float* Af = (const float*)Av;
  const u32*   Ap = (const u32*)Av;
  if (GROUPED){ Bhp += (long)e*strideB; Blp += (long)e*strideB; }
  const float* biasp = bias ? (GROUPED ? bias + (long)e*strideBias : bias) : nullptr;

  extern __shared__ u16 smem[];
  u16* Ah = smem;                 // BM*SW
  u16* Al = Ah + BM*SW;
  u16* Bh = Al + BM*SW;           // 64*SW
  u16* Bl = Bh + 64*SW;

  int tid = threadIdx.x;
  int w = tid >> 6, ln = tid & 63;
  int wm = w >> 1, wn = w & 1;
  int lr = ln & 15, lh = ln >> 4;
  int srow = tid >> 2, sseg = tid & 3;

  int bgrow = bn*64 + srow;
  bool bok = bgrow < N;
  int agrow = bm*BM + srow;
  bool aok = (tid < BM*4) && (agrow < rows);
  long arow = 0;
  if (aok) arow = INDIRECT ? (long)map[row0 + agrow] : (long)(row0 + agrow);

  const f32x4 z4 = {0.f,0.f,0.f,0.f};
  f32x4 acc0 = z4, acc1 = z4;
  const s16x8 z8 = {0,0,0,0,0,0,0,0};

  // two register stage-sets (static names -> no scratch)
  s16x8 rBh0[NSEG], rBl0[NSEG], rBh1[NSEG], rBl1[NSEG];
  uint4 rA00[NSEG], rA10[NSEG], rA01[NSEG], rA11[NSEG];
  float4 rP00[NSEG], rP10[NSEG], rP01[NSEG], rP11[NSEG];
  float rinv0[NSEG], rinv1[NSEG];

  auto load_st = [&](s16x8 (&rBh)[NSEG], s16x8 (&rBl)[NSEG],
                     uint4 (&rA0)[NSEG], uint4 (&rA1)[NSEG],
                     float4 (&rP0)[NSEG], float4 (&rP1)[NSEG],
                     float (&rinv)[NSEG], int t){
    int k0 = t*BK;
    #pragma unroll
    for (int s=0; s<NSEG; s++){
      int kk = k0 + s*32 + sseg*8;
      bool kok = kk < K;               // K % 8 == 0 always
      rBh[s] = z8; rBl[s] = z8;
      if (bok && kok){
        rBh[s] = *(const s16x8*)&Bhp[(long)bgrow*ldb + kk];
        rBl[s] = *(const s16x8*)&Blp[(long)bgrow*ldb + kk];
      }
      if (tid < BM*4){
        rA0[s] = make_uint4(0,0,0,0); rA1[s] = make_uint4(0,0,0,0);
        if (ASRC==2 || ASRC==3 || ASRC==5){
          rP0[s] = make_float4(0.f,0.f,0.f,0.f); rP1[s] = rP0[s]; rinv[s] = 0.f;
        }
        if (aok && kok){
          if (ASRC == 1){
            rA0[s] = *(const uint4*)&Ap[arow*lda + kk];
            rA1[s] = *(const uint4*)&Ap[arow*lda + kk + 4];
          } else if (ASRC == 5){
            long aoff = arow*(long)lda + kk;
            rA0[s] = *(const uint4*)&Af[aoff];                 // O0 [kk..kk+3]
            rA1[s] = *(const uint4*)&Af[aoff + 4];             // O0 [kk+4..kk+7]
            rP0[s] = ld4(&Af[(long)NTOK*DM + aoff]);           // O1 [kk..kk+3]
            rP1[s] = ld4(&Af[(long)NTOK*DM + aoff + 4]);       // O1 [kk+4..kk+7]
            int h = kk >> 5;                                   // head of this 8-chunk
            float l0 = pos[arow*8 + h];
            float l1 = pos[65536 + arow*8 + h];
            rinv[s] = 1.f / (l0 + l1);
          } else {
            long aoff = (ASRC==3 ? (long)(arow>>2) : arow)*lda + kk;
            rA0[s] = *(const uint4*)&Af[aoff];
            rA1[s] = *(const uint4*)&Af[aoff + 4];
            if (ASRC==2 || ASRC==3){
              long poff = (long)(arow>>2)*DM + kk;
              rP0[s] = ld4(&pos[poff]);
              rP1[s] = ld4(&pos[poff + 4]);
            }
          }
        }
      }
    }
  };

  auto write_st = [&](s16x8 (&rBh)[NSEG], s16x8 (&rBl)[NSEG],
                      uint4 (&rA0)[NSEG], uint4 (&rA1)[NSEG],
                      float4 (&rP0)[NSEG], float4 (&rP1)[NSEG],
                      float (&rinv)[NSEG]){
    #pragma unroll
    for (int s=0; s<NSEG; s++){
      *(s16x8*)&Bh[srow*SW + s*32 + sseg*8] = rBh[s];
      *(s16x8*)&Bl[srow*SW + s*32 + sseg*8] = rBl[s];
      if (tid < BM*4){
        s16x8 hv, lv;
        if (ASRC == 1){
          u32 ws[8] = {rA0[s].x,rA0[s].y,rA0[s].z,rA0[s].w,rA1[s].x,rA1[s].y,rA1[s].z,rA1[s].w};
          #pragma unroll
          for (int t=0;t<8;t++){ hv[t]=(short)(ws[t]&0xFFFFu); lv[t]=(short)(ws[t]>>16); }
        } else {
          float xs[8] = {__uint_as_float(rA0[s].x),__uint_as_float(rA0[s].y),
                         __uint_as_float(rA0[s].z),__uint_as_float(rA0[s].w),
                         __uint_as_float(rA1[s].x),__uint_as_float(rA1[s].y),
                         __uint_as_float(rA1[s].z),__uint_as_float(rA1[s].w)};
          if (ASRC==2 || ASRC==3){
            xs[0]+=rP0[s].x; xs[1]+=rP0[s].y; xs[2]+=rP0[s].z; xs[3]+=rP0[s].w;
            xs[4]+=rP1[s].x; xs[5]+=rP1[s].y; xs[6]+=rP1[s].z; xs[7]+=rP1[s].w;
          }
          if (ASRC==5){
            float iv = rinv[s];
            xs[0]=(xs[0]+rP0[s].x)*iv; xs[1]=(xs[1]+rP0[s].y)*iv;
            xs[2]=(xs[2]+rP0[s].z)*iv; xs[3]=(xs[3]+rP0[s].w)*iv;
            xs[4]=(xs[4]+rP1[s].x)*iv; xs[5]=(xs[5]+rP1[s].y)*iv;
            xs[6]=(xs[6]+rP1[s].z)*iv; xs[7]=(xs[7]+rP1[s].w)*iv;
          }
          #pragma unroll
          for (int t=0;t<8;t++){ u16 hh,ll; splitf(xs[t],hh,ll); hv[t]=(short)hh; lv[t]=(short)ll; }
        }
        *(s16x8*)&Ah[srow*SW + s*32 + sseg*8] = hv;
        *(s16x8*)&Al[srow*SW + s*32 + sseg*8] = lv;
      }
    }
  };

  auto compute_tile = [&](){
    #pragma unroll
    for (int s=0; s<NSEG; s++){
      int co = s*32 + lh*8;
      s16x8 a0h = *(const s16x8*)&Ah[(wm*16 + lr)*SW + co];
      s16x8 a0l = *(const s16x8*)&Al[(wm*16 + lr)*SW + co];
      s16x8 b0h = *(const s16x8*)&Bh[(wn*32      + lr)*SW + co];
      s16x8 b1h = *(const s16x8*)&Bh[(wn*32 + 16 + lr)*SW + co];
      s16x8 b0l = *(const s16x8*)&Bl[(wn*32      + lr)*SW + co];
      s16x8 b1l = *(const s16x8*)&Bl[(wn*32 + 16 + lr)*SW + co];
      acc0 = __builtin_amdgcn_mfma_f32_16x16x32_bf16(a0h, b0h, acc0, 0,0,0);
      acc1 = __builtin_amdgcn_mfma_f32_16x16x32_bf16(a0h, b1h, acc1, 0,0,0);
      acc0 = __builtin_amdgcn_mfma_f32_16x16x32_bf16(a0h, b0l, acc0, 0,0,0);
      acc1 = __builtin_amdgcn_mfma_f32_16x16x32_bf16(a0h, b1l, acc1, 0,0,0);
      acc0 = __builtin_amdgcn_mfma_f32_16x16x32_bf16(a0l, b0h, acc0, 0,0,0);
      acc1 = __builtin_amdgcn_mfma_f32_16x16x32_bf16(a0l, b1h, acc1, 0,0,0);
    }
  };

  const int NT = (K + BK - 1) / BK;
  load_st(rBh0,rBl0,rA00,rA10,rP00,rP10,rinv0, 0);
  load_st(rBh1,rBl1,rA01,rA11,rP01,rP11,rinv1, 1);
  for (int t = 0; t < NT; t += 2){
    // phase A: tile t (from S0)
    write_st(rBh0,rBl0,rA00,rA10,rP00,rP10,rinv0);
    __syncthreads();
    load_st(rBh0,rBl0,rA00,rA10,rP00,rP10,rinv0, t+2);  // 2-deep prefetch (kok-guarded)
    compute_tile();
    __syncthreads();
    // phase B: tile t+1 (from S1)
    if (t+1 < NT){
      write_st(rBh1,rBl1,rA01,rA11,rP01,rP11,rinv1);
      __syncthreads();
      load_st(rBh1,rBl1,rA01,rA11,rP01,rP11,rinv1, t+3);
      compute_tile();
      __syncthreads();
    }
  }

  int c0 = bn*64 + wn*32 + lr;
  int c1 = c0 + 16;
  float bv0 = (biasp && c0 < N) ? biasp[c0] : 0.f;
  float bv1 = (biasp && c1 < N) ? biasp[c1] : 0.f;
  int rbase = bm*BM + wm*16 + lh*4;
  auto stc = [&](int gr, int gc, float vv){
    if (gr < rows && gc < N){
      float t = RELU ? fmaxf(vv, 0.f) : vv;
      if (CDST == 1){
        ((u32*)Cv)[(long)(row0+gr)*ldc + gc] = packf(t);
      } else if (CDST == 2){
        int ts = jmap[row0+gr];
        ((float*)Cv)[(long)ts*ldc + gc] = t * sflat[ts];
      } else {
        ((float*)Cv)[(long)(row0+gr)*ldc + gc] = t;
      }
    }
  };
  #pragma unroll
  for (int r = 0; r < 4; r++){
    stc(rbase + r, c0, acc0[r] + bv0);
    stc(rbase + r, c1, acc1[r] + bv1);
  }
}

// ---- named GEMM wrappers ----
__global__ __launch_bounds__(256) void gemm_in(const float* A, const u16* Bh_, const u16* Bl_,
    const float* bias, float* C){
  sgemm_body<false,false,0,false,0,32>(A, NCIN, nullptr, Bh_, Bl_, NCIN, bias, C, DM,
      NTOK, DM, NCIN, nullptr, nullptr, nullptr, nullptr, nullptr, 0, 0, 0);
}

__global__ __launch_bounds__(256) void gemm_out_k(const float* A, const u16* Bh_, const u16* Bl_,
    const float* bias, float* C){
  sgemm_body<false,false,0,false,0,32>(A, DM, nullptr, Bh_, Bl_, DM, bias, C, NCIN,
      NTOK, NCIN, DM, nullptr, nullptr, nullptr, nullptr, nullptr, 0, 0, 0);
}

// wos/woc: A = split-KV attention partials, merge fused into staging (ASRC=5)
__global__ __launch_bounds__(256) void gemm_wos(const float* OpB, const float* lB,
    const u16* Bh_, const u16* Bl_, const float* bias, float* C){
  sgemm_body<false,false,5,false,0,32>(OpB, DM, lB, Bh_, Bl_, DM, bias, C, DM,
      NTOK, DM, DM, nullptr, nullptr, nullptr, nullptr, nullptr, 0, 0, 0);
}

__global__ __launch_bounds__(256) void gemm_woc(const float* OpB, const float* lB,
    const u16* Bh_, const u16* Bl_, const float* bias, float* C){
  sgemm_body<false,false,5,false,0,32>(OpB, DM, lB, Bh_, Bl_, DM, bias, C, DM,
      NTOK, DM, DM, nullptr, nullptr, nullptr, nullptr, nullptr, 0, 0, 0);
}

template<int MQ, int MK>
__device__ __forceinline__ void qkv_body(const float* Aq, const float* Ak, const float* Avv,
    const float* pos, const u16* Bwh, const u16* Bwl, const float* bias,
    u32* Cq, u32* Ck, u32* Cvv){
  int z = blockIdx.z;
  const float* A = z==0 ? Aq : (z==1 ? Ak : Avv);
  u32* C = z==0 ? Cq : (z==1 ? Ck : Cvv);
  const u16* Bph = Bwh + (long)z*256*DM;
  const u16* Bpl = Bwl + (long)z*256*DM;
  const float* bp = bias + z*256;
  int mode = z==0 ? MQ : (z==1 ? MK : 0);
  if (mode == 3)
    sgemm_body<false,false,3,false,1,32>(A, DM, pos, Bph, Bpl, DM, bp, C, DM,
        NTOK, DM, DM, nullptr, nullptr, nullptr, nullptr, nullptr, 0, 0, 0);
  else if (mode == 2)
    sgemm_body<false,false,2,false,1,32>(A, DM, pos, Bph, Bpl, DM, bp, C, DM,
        NTOK, DM, DM, nullptr, nullptr, nullptr, nullptr, nullptr, 0, 0, 0);
  else
    sgemm_body<false,false,0,false,1,32>(A, DM, pos, Bph, Bpl, DM, bp, C, DM,
        NTOK, DM, DM, nullptr, nullptr, nullptr, nullptr, nullptr, 0, 0, 0);
}

__global__ __launch_bounds__(256) void gemm_qkv_s(const float* Aq, const float* Ak,
    const float* Avv, const float* pos, const u16* Bwh, const u16* Bwl, const float* bias,
    u32* Cq, u32* Ck, u32* Cvv){
  qkv_body<3,2>(Aq, Ak, Avv, pos, Bwh, Bwl, bias, Cq, Ck, Cvv);
}
__global__ __launch_bounds__(256) void gemm_qkv_c(const float* Aq, const float* Ak,
    const float* Avv, const float* pos, const u16* Bwh, const u16* Bwl, const float* bias,
    u32* Cq, u32* Ck, u32* Cvv){
  qkv_body<2,2>(Aq, Ak, Avv, pos, Bwh, Bwl, bias, Cq, Ck, Cvv);
}

__global__ __launch_bounds__(256) void gemm_m1(const float* A, const u16* Bh_, const u16* Bl_,
    const float* bias, u32* C, const int* map, const int* cnt, const int* offs){
  sgemm_body<true,true,0,true,1,32>(A, DM, nullptr, Bh_, Bl_, DM, bias, C, NDFF,
      0, NDFF, DM, map, cnt, offs, nullptr, nullptr, 262144L, NDFF, blockIdx.z);
}

__global__ __launch_bounds__(256) void gemm_m2(const u32* A, const u16* Bh_, const u16* Bl_,
    const float* bias, float* C, const int* cnt, const int* offs,
    const int* jmap, const float* sflat){
  sgemm_body<true,false,1,false,2,64>(A, NDFF, nullptr, Bh_, Bl_, NDFF, bias, C, DM,
      0, DM, NDFF, nullptr, cnt, offs, jmap, sflat, 262144L, DM, blockIdx.z);
}

// ---------------- MFMA flash attention, split-bf16, dh=32, SPLIT-KV ----------------
// Bounded-score softmax (no max-shift; logits provably small for this model).
__global__ __launch_bounds__(256) void attn_mfma(const u32* __restrict__ Q,
    const u32* __restrict__ Kb, const u32* __restrict__ Vb,
    float* __restrict__ OpBase, float* __restrict__ lBase)
{
  __shared__ u16 Kh[64*40], Kl[64*40];
  __shared__ u16 Vh[32*72], Vl[32*72];
  __shared__ u16 Ph[4][16*72], Pl[4][16*72];

  int qt = blockIdx.x, bh = blockIdx.y, z = blockIdx.z;
  int b = bh >> 3, h = bh & 7;
  int tid = threadIdx.x;
  int wv = tid >> 6, ln = tid & 63;
  int lr = ln & 15, lh = ln >> 4;
  const float scale = 0.17677669529663687f;  // 1/sqrt(32)
  int kt0 = z*8, kt1 = z*8 + 8;
  float* Op   = OpBase + (long)z*NTOK*DM;
  float* lArr = lBase + (long)z*65536;

  s16x8 qh, ql;
  {
    long qrow = ((long)((qt*64 + wv*16 + lr)*NB + b))*DM + h*32 + lh*8;
    uint4 p0 = *(const uint4*)&Q[qrow];
    uint4 p1 = *(const uint4*)&Q[qrow + 4];
    u32 ws[8] = {p0.x,p0.y,p0.z,p0.w,p1.x,p1.y,p1.z,p1.w};
    #pragma unroll
    for (int t=0;t<8;t++){ qh[t]=(short)(ws[t]&0xFFFFu); ql[t]=(short)(ws[t]>>16); }
  }

  int skey = tid >> 2, soct = tid & 3;
  int vkey0 = tid >> 3,        vd0 = (tid & 7) << 2;
  int vkey1 = (tid + 256) >> 3, vd1 = ((tid + 256) & 7) << 2;

  uint4 rK0, rK1, rV0, rV1;

  auto load_kv = [&](int kt){
    long gk = ((long)((kt*64 + skey)*NB + b))*DM + h*32 + soct*8;
    rK0 = *(const uint4*)&Kb[gk];
    rK1 = *(const uint4*)&Kb[gk + 4];
    rV0 = *(const uint4*)&Vb[((long)((kt*64 + vkey0)*NB + b))*DM + h*32 + vd0];
    rV1 = *(const uint4*)&Vb[((long)((kt*64 + vkey1)*NB + b))*DM + h*32 + vd1];
  };

  auto write_kv = [&](){
    u32 ws[8] = {rK0.x,rK0.y,rK0.z,rK0.w,rK1.x,rK1.y,rK1.z,rK1.w};
    s16x8 hv, lv;
    #pragma unroll
    for (int t=0;t<8;t++){ hv[t]=(short)(ws[t]&0xFFFFu); lv[t]=(short)(ws[t]>>16); }
    *(s16x8*)&Kh[skey*40 + soct*8] = hv;
    *(s16x8*)&Kl[skey*40 + soct*8] = lv;
    u32 v0[4] = {rV0.x,rV0.y,rV0.z,rV0.w};
    u32 v1[4] = {rV1.x,rV1.y,rV1.z,rV1.w};
    #pragma unroll
    for (int t=0;t<4;t++){
      Vh[(vd0+t)*72 + vkey0] = (u16)(v0[t]&0xFFFFu);
      Vl[(vd0+t)*72 + vkey0] = (u16)(v0[t]>>16);
      Vh[(vd1+t)*72 + vkey1] = (u16)(v1[t]&0xFFFFu);
      Vl[(vd1+t)*72 + vkey1] = (u16)(v1[t]>>16);
    }
  };

  const f32x4 z4 = {0.f,0.f,0.f,0.f};
  f32x4 oacc0 = z4, oacc1 = z4;
  float lp[4] = {0.f,0.f,0.f,0.f};

  load_kv(kt0);
  for (int kt = kt0; kt < kt1; kt++){
    write_kv();
    __syncthreads();
    if (kt + 1 < kt1) load_kv(kt + 1);

    #pragma unroll
    for (int s16t=0; s16t<4; s16t++){
      s16x8 kbh = *(const s16x8*)&Kh[(s16t*16 + lr)*40 + lh*8];
      s16x8 kbl = *(const s16x8*)&Kl[(s16t*16 + lr)*40 + lh*8];
      f32x4 a = z4;
      a = __builtin_amdgcn_mfma_f32_16x16x32_bf16(qh, kbh, a, 0,0,0);
      a = __builtin_amdgcn_mfma_f32_16x16x32_bf16(qh, kbl, a, 0,0,0);
      a = __builtin_amdgcn_mfma_f32_16x16x32_bf16(ql, kbh, a, 0,0,0);
      #pragma unroll
      for (int r=0;r<4;r++){
        float p = __expf(a[r]*scale);     // no max-shift: scores bounded
        lp[r] += p;
        u16 hh,ll; splitf(p,hh,ll);
        int off = (lh*4 + r)*72 + s16t*16 + lr;
        Ph[wv][off] = hh;
        Pl[wv][off] = ll;
      }
    }
    #pragma unroll
    for (int ks=0; ks<2; ks++){
      s16x8 pah = *(const s16x8*)&Ph[wv][lr*72 + ks*32 + lh*8];
      s16x8 pal = *(const s16x8*)&Pl[wv][lr*72 + ks*32 + lh*8];
      s16x8 vh0 = *(const s16x8*)&Vh[lr*72      + ks*32 + lh*8];
      s16x8 vl0 = *(const s16x8*)&Vl[lr*72      + ks*32 + lh*8];
      s16x8 vh1 = *(const s16x8*)&Vh[(16+lr)*72 + ks*32 + lh*8];
      s16x8 vl1 = *(const s16x8*)&Vl[(16+lr)*72 + ks*32 + lh*8];
      oacc0 = __builtin_amdgcn_mfma_f32_16x16x32_bf16(pah, vh0, oacc0, 0,0,0);
      oacc0 = __builtin_amdgcn_mfma_f32_16x16x32_bf16(pah, vl0, oacc0, 0,0,0);
      oacc0 = __builtin_amdgcn_mfma_f32_16x16x32_bf16(pal, vh0, oacc0, 0,0,0);
      oacc1 = __builtin_amdgcn_mfma_f32_16x16x32_bf16(pah, vh1, oacc1, 0,0,0);
      oacc1 = __builtin_amdgcn_mfma_f32_16x16x32_bf16(pah, vl1, oacc1, 0,0,0);
      oacc1 = __builtin_amdgcn_mfma_f32_16x16x32_bf16(pal, vh1, oacc1, 0,0,0);
    }
    __syncthreads();
  }
  #pragma unroll
  for (int mask=1; mask<=8; mask<<=1){
    #pragma unroll
    for (int r=0;r<4;r++) lp[r] += __shfl_xor(lp[r], mask);
  }
  #pragma unroll
  for (int r=0;r<4;r++){
    int q = qt*64 + wv*16 + lh*4 + r;
    long n = (long)q*NB + b;
    long orow = n*DM + h*32;
    Op[orow + lr]      = oacc0[r];
    Op[orow + 16 + lr] = oacc1[r];
    if (lr == 0) lArr[n*8 + h] = lp[r];
  }
}

// ---------------- LN / gate helpers ----------------
__device__ __forceinline__ float wave_sum(float v){
  #pragma unroll
  for (int m=1; m<64; m<<=1) v += __shfl_xor(v, m);
  return v;
}

__device__ __forceinline__ float4 ln_finish(float4 a, const float* g, const float* beta, int lane){
  float sum = wave_sum(a.x+a.y+a.z+a.w);
  float sq  = wave_sum(a.x*a.x + a.y*a.y + a.z*a.z + a.w*a.w);
  float mean = sum * (1.f/DM);
  float var  = sq * (1.f/DM) - mean*mean;
  float inv = 1.0f / sqrtf(var + 1e-5f);
  float4 gg = ld4(&g[lane*4]);
  float4 bb = ld4(&beta[lane*4]);
  float4 ov;
  ov.x = (a.x-mean)*inv*gg.x + bb.x;
  ov.y = (a.y-mean)*inv*gg.y + bb.y;
  ov.z = (a.z-mean)*inv*gg.z + bb.z;
  ov.w = (a.w-mean)*inv*gg.w + bb.w;
  return ov;
}

__device__ __forceinline__ void gate_from_regs(float4 ov, int row, int lane,
    const float* GW, const float* GB, float* scores, int* topi){
  float lg[8];
  #pragma unroll
  for (int e=0; e<8; e++){
    float4 wv = ld4(&GW[e*DM + lane*4]);
    lg[e] = ov.x*wv.x + ov.y*wv.y + ov.z*wv.z + ov.w*wv.w;
  }
  #pragma unroll
  for (int mask=1; mask<64; mask<<=1){
    #pragma unroll
    for (int e=0; e<8; e++) lg[e] += __shfl_xor(lg[e], mask);
  }
  #pragma unroll
  for (int e=0; e<8; e++) lg[e] += GB[e];
  int i0 = 0; float v0 = lg[0];
  #pragma unroll
  for (int e=1; e<8; e++) if (lg[e] > v0){ v0 = lg[e]; i0 = e; }
  int i1 = -1; float v1 = -1e30f;
  #pragma unroll
  for (int e=0; e<8; e++) if (e != i0 && lg[e] > v1){ v1 = lg[e]; i1 = e; }
  if (lane == 0){
    float ee = expf(v1 - v0);
    float inv = 1.f/(1.f + ee);
    scores[row*2]   = inv;
    scores[row*2+1] = ee*inv;
    topi[row*2]   = i0;
    topi[row*2+1] = i1;
  }
}

__global__ __launch_bounds__(256) void add_ln_le(const float* __restrict__ A,
    const float* __restrict__ Bv, const float* __restrict__ g, const float* __restrict__ beta,
    float* __restrict__ out)
{
  int row = blockIdx.x*4 + (threadIdx.x >> 6);
  int lane = threadIdx.x & 63;
  float4 a = ld4(&A[(long)(row>>2)*DM + lane*4]);
  float4 b = ld4(&Bv[(long)row*DM + lane*4]);
  a.x+=b.x; a.y+=b.y; a.z+=b.z; a.w+=b.w;
  float4 ov = ln_finish(a, g, beta, lane);
  st4(&out[(long)row*DM + lane*4], ov);
}

__global__ __launch_bounds__(256) void add_ln_gate(const float* __restrict__ A,
    const float* __restrict__ Bv, const float* __restrict__ g, const float* __restrict__ beta,
    float* __restrict__ out, const float* __restrict__ GW, const float* __restrict__ GB,
    float* __restrict__ scores, int* __restrict__ topi)
{
  int row = blockIdx.x*4 + (threadIdx.x >> 6);
  int lane = threadIdx.x & 63;
  float4 a = ld4(&A[(long)row*DM + lane*4]);
  float4 b = ld4(&Bv[(long)row*DM + lane*4]);
  a.x+=b.x; a.y+=b.y; a.z+=b.z; a.w+=b.w;
  float4 ov = ln_finish(a, g, beta, lane);
  st4(&out[(long)row*DM + lane*4], ov);
  gate_from_regs(ov, row, lane, GW, GB, scores, topi);
}

__global__ __launch_bounds__(256) void moe_ln_gate_k(const float* __restrict__ base,
    const float* __restrict__ yt,
    const float* __restrict__ g, const float* __restrict__ beta, float* __restrict__ out,
    const float* __restrict__ GW, const float* __restrict__ GB,
    float* __restrict__ scores2, int* __restrict__ topi2)
{
  int row = blockIdx.x*4 + (threadIdx.x >> 6);
  int lane = threadIdx.x & 63;
  float4 a  = ld4(&base[(long)row*DM + lane*4]);
  float4 y0 = ld4(&yt[(long)(row*2)*DM + lane*4]);
  float4 y1 = ld4(&yt[(long)(row*2+1)*DM + lane*4]);
  a.x += y0.x + y1.x;
  a.y += y0.y + y1.y;
  a.z += y0.z + y1.z;
  a.w += y0.w + y1.w;
  float4 ov = ln_finish(a, g, beta, lane);
  st4(&out[(long)row*DM + lane*4], ov);
  gate_from_regs(ov, row, lane, GW, GB, scores2, topi2);
}

__global__ __launch_bounds__(256) void moe_ln_fin_k(const float* __restrict__ base,
    const float* __restrict__ yt,
    const float* __restrict__ g, const float* __restrict__ beta, float* __restrict__ out)
{
  int row = blockIdx.x*4 + (threadIdx.x >> 6);
  int lane = threadIdx.x & 63;
  float4 a  = ld4(&base[(long)row*DM + lane*4]);
  float4 y0 = ld4(&yt[(long)(row*2)*DM + lane*4]);
  float4 y1 = ld4(&yt[(long)(row*2+1)*DM + lane*4]);
  a.x += y0.x + y1.x;
  a.y += y0.y + y1.y;
  a.z += y0.z + y1.z;
  a.w += y0.w + y1.w;
  float4 ov = ln_finish(a, g, beta, lane);
  st4(&out[(long)row*DM + lane*4], ov);
}

__global__ void offs_assign(const int* __restrict__ topi, int* __restrict__ cnt_g,
    int* __restrict__ offs_g, int* __restrict__ map, int* __restrict__ jmap)
{
  __shared__ int hist[72];
  __shared__ int offs[8];
  __shared__ int c2[8];
  int tid = threadIdx.x;
  if (tid < 72) hist[tid] = 0;
  __syncthreads();
  for (int idx = tid; idx < 2*NTOK; idx += 256){
    int e = topi[idx];
    atomicAdd(&hist[e*9 + (tid & 7)], 1);
  }
  __syncthreads();
  if (tid == 0){
    int o = 0;
    #pragma unroll
    for (int e=0; e<8; e++){
      int c = 0;
      #pragma unroll
      for (int s=0; s<8; s++) c += hist[e*9 + s];
      cnt_g[e] = c;
      offs[e] = o;
      offs_g[e] = o;
      o += c;
      c2[e] = 0;
    }
  }
  __syncthreads();
  for (int n = tid; n < NTOK; n += 256){
    #pragma unroll
    for (int j=0; j<2; j++){
      int e = topi[n*2+j];
      int slot = atomicAdd(&c2[e], 1);
      int r = offs[e] + slot;
      map[r] = n;
      jmap[r] = n*2 + j;
    }
  }
}

// =================================================================
extern "C" void kernel_launch(void* const* d_in, const int* in_sizes, int n_in,
                              void* d_out, int out_size, void* d_ws, size_t ws_size,
                              hipStream_t stream)
{
  const float* x      = (const float*)d_in[0];
  const float* Wi     = (const float*)d_in[1];
  const float* bi     = (const float*)d_in[2];
  const float* le     = (const float*)d_in[3];
  const float* Wqkv_s = (const float*)d_in[4];
  const float* bqkv_s = (const float*)d_in[5];
  const float* Wo_s   = (const float*)d_in[6];
  const float* bo_s   = (const float*)d_in[7];
  const float* Wqkv_c = (const float*)d_in[8];
  const float* bqkv_c = (const float*)d_in[9];
  const float* Wo_c   = (const float*)d_in[10];
  const float* bo_c   = (const float*)d_in[11];
  const float* ln_g   = (const float*)d_in[12];
  const float* ln_b   = (const float*)d_in[13];
  const float* gw1    = (const float*)d_in[14];
  const float* gb1    = (const float*)d_in[15];
  const float* W1a    = (const float*)d_in[16];
  const float* b1a    = (const float*)d_in[17];
  const float* W2a    = (const float*)d_in[18];
  const float* b2a    = (const float*)d_in[19];
  const float* gw2    = (const float*)d_in[20];
  const float* gb2    = (const float*)d_in[21];
  const float* W1b    = (const float*)d_in[22];
  const float* b1b    = (const float*)d_in[23];
  const float* W2b    = (const float*)d_in[24];
  const float* b2b    = (const float*)d_in[25];
  const float* Wout   = (const float*)d_in[26];
  const float* bout   = (const float*)d_in[27];

  float* w = (float*)d_ws;
  const long SZ = 1048576;            // NTOK*DM
  float* pos  = w;                    // 262144
  float* src  = pos  + 262144;
  float* t2s  = src  + SZ;
  float* tgtA = t2s  + SZ;
  float* dec  = tgtA + SZ;
  float* od   = dec;                  // ALIAS: od and dec have disjoint live ranges
  float* od2  = dec  + SZ;
  float* yt   = od2  + SZ;            // 2,097,152 fp32
  float* scoresA = yt + 2097152;      // 8192
  float* scoresB = scoresA + 8192;    // 8192
  u16* wsp  = (u16*)(scoresB + 8192);
  u16* W1ah = wsp;             u16* W1al = wsp + 2097152;
  u16* W1bh = wsp + 4194304;   u16* W1bl = wsp + 6291456;
  u16* W2ah = wsp + 8388608;   u16* W2al = wsp + 10485760;
  u16* W2bh = wsp + 12582912;  u16* W2bl = wsp + 14680064;
  u16* dwp  = wsp + 16777216;
  u16* Wih   = dwp;            u16* Wil   = dwp + 69632;
  u16* Wqsh  = dwp + 139264;   u16* Wqsl  = dwp + 335872;
  u16* Wosh  = dwp + 532480;   u16* Wosl  = dwp + 598016;
  u16* Wqch  = dwp + 663552;   u16* Wqcl  = dwp + 860160;
  u16* Woch  = dwp + 1056768;  u16* Wocl  = dwp + 1122304;
  u16* Wouth = dwp + 1187840;  u16* Woutl = dwp + 1257472;
  // overlay region R: 8,388,608 floats
  float* R   = (float*)(dwp + 1327104);
  float* tok = R;                     // dead before q written
  u32*  q    = (u32*)R;               // packed pairs
  u32*  k    = (u32*)(R + SZ);        // packed; reused as t2c (fp32) after attn
  u32*  v    = (u32*)(R + 2*SZ);      // packed pairs
  float* OpB = R + 4*SZ;              // split-KV partial O: 2 x SZ fp32
  float* lB  = R + 6*SZ;              // l halves: 2 x 65536
  u32*  hg   = (u32*)R;               // MoE phase (q..Op dead)
  float* rec = R;                     // final
  int* ip    = (int*)(R + 8388608);
  int* topiA = ip;
  int* topiB = ip + 8192;
  int* map   = ip + 16384;
  int* jmapA = ip + 24576;
  int* jmapB = ip + 32768;
  int* cnts  = ip + 40960;
  int* offsg = ip + 40992;

  dim3 blk(256);
  dim3 gDense(4, 128, 1);
  dim3 gQKV(4, 128, 3);
  dim3 gMoe1(16, 128, 8);
  dim3 gMoe2(4, 128, 8);
  dim3 gAttn(16, 32, 2);

  pos_kernel<<<NHW, DM, 0, stream>>>(pos);
  tin_kernel<<<(NTOK*NCIN + 255)/256, blk, 0, stream>>>(x, tok);

  tconv_kernel<<<dim3(32, 8, 8), blk, 0, stream>>>(W1a, W1ah, W1al, DM,   NDFF);
  tconv_kernel<<<dim3(32, 8, 8), blk, 0, stream>>>(W1b, W1bh, W1bl, DM,   NDFF);
  tconv_kernel<<<dim3(8, 32, 8), blk, 0, stream>>>(W2a, W2ah, W2al, NDFF, DM);
  tconv_kernel<<<dim3(8, 32, 8), blk, 0, stream>>>(W2b, W2bh, W2bl, NDFF, DM);
  wsplit_kernel<<<272, blk, 0, stream>>>(Wi,     Wih,   Wil,   69632);
  wsplit_kernel<<<768, blk, 0, stream>>>(Wqkv_s, Wqsh,  Wqsl,  196608);
  wsplit_kernel<<<256, blk, 0, stream>>>(Wo_s,   Wosh,  Wosl,  65536);
  wsplit_kernel<<<768, blk, 0, stream>>>(Wqkv_c, Wqch,  Wqcl,  196608);
  wsplit_kernel<<<256, blk, 0, stream>>>(Wo_c,   Woch,  Wocl,  65536);
  wsplit_kernel<<<272, blk, 0, stream>>>(Wout,   Wouth, Woutl, 69632);

  gemm_in<<<gDense, blk, GEMM_SMEM32, stream>>>(tok, Wih, Wil, bi, src);

  gemm_qkv_s<<<gQKV, blk, GEMM_SMEM32, stream>>>(le, src, src, pos, Wqsh, Wqsl, bqkv_s, q, k, v);
  attn_mfma<<<gAttn, blk, 0, stream>>>(q, k, v, OpB, lB);
  gemm_wos<<<gDense, blk, GEMM_SMEM32, stream>>>(OpB, lB, Wosh, Wosl, bo_s, t2s);

  const float* decIn = src;
  for (int i = 0; i < 2; i++){
    int* cntA = cnts + (i*2)*8;   int* offsA = offsg + (i*2)*8;
    int* cntB = cnts + (i*2+1)*8; int* offsB = offsg + (i*2+1)*8;

    add_ln_le<<<1024, blk, 0, stream>>>(le, t2s, ln_g + (4*i)*DM, ln_b + (4*i)*DM, tgtA);
    gemm_qkv_c<<<gQKV, blk, GEMM_SMEM32, stream>>>(tgtA, decIn, decIn, pos, Wqch, Wqcl, bqkv_c, q, k, v);
    attn_mfma<<<gAttn, blk, 0, stream>>>(q, k, v, OpB, lB);
    gemm_woc<<<gDense, blk, GEMM_SMEM32, stream>>>(OpB, lB, Woch, Wocl, bo_c, (float*)k);
    add_ln_gate<<<1024, blk, 0, stream>>>(tgtA, (float*)k, ln_g + (4*i+1)*DM, ln_b + (4*i+1)*DM, od,
        gw1, gb1, scoresA, topiA);

    offs_assign<<<1, blk, 0, stream>>>(topiA, cntA, offsA, map, jmapA);
    gemm_m1<<<gMoe1, blk, GEMM_SMEM32, stream>>>(od, W1ah, W1al, b1a, hg, map, cntA, offsA);
    gemm_m2<<<gMoe2, blk, GEMM_SMEM64, stream>>>(hg, W2ah, W2al, b2a, yt, cntA, offsA,
        jmapA, scoresA);
    moe_ln_gate_k<<<1024, blk, 0, stream>>>(od, yt,
        ln_g + (4*i+2)*DM, ln_b + (4*i+2)*DM, od2, gw2, gb2, scoresB, topiB);

    offs_assign<<<1, blk, 0, stream>>>(topiB, cntB, offsB, map, jmapB);
    gemm_m1<<<gMoe1, blk, GEMM_SMEM32, stream>>>(od2, W1bh, W1bl, b1b, hg, map, cntB, offsB);
    gemm_m2<<<gMoe2, blk, GEMM_SMEM64, stream>>>(hg, W2bh, W2bl, b2b, yt, cntB, offsB,
        jmapB, scoresB);
    moe_ln_fin_k<<<1024, blk, 0, stream>>>(od2, yt,
        ln_g + (4*i+3)*DM, ln_b + (4*i+3)*DM, dec);

    decIn = dec;
  }

  gemm_out_k<<<dim3(5,128,1), blk, GEMM_SMEM32, stream>>>(dec, Wouth, Woutl, bout, rec);
  tout_kernel<<<(NTOK*NCIN + 255)/256, blk, 0, stream>>>(rec, (float*)d_out);
}

// Round 27
// 627.303 us; speedup vs baseline: 1.0301x; 1.0301x over previous
//
#include <hip/hip_runtime.h>

#define NHW 1024
#define NB 4
#define DM 256
#define NTOK 4096      // NHW * NB
#define NCIN 272
#define NDFF 1024

typedef unsigned short u16;
typedef unsigned int u32;
typedef __attribute__((ext_vector_type(8))) short s16x8;
typedef __attribute__((ext_vector_type(4))) float f32x4;

static const int GEMM_SMEM32 = (32+32+64+64)*56*2;   // 21504 B (BK=32)
static const int GEMM_SMEM64 = (32+32+64+64)*72*2;   // 27648 B (BK=64)

__device__ __forceinline__ float4 ld4(const float* p){ return *(const float4*)p; }
__device__ __forceinline__ void st4(float* p, float4 v){ *(float4*)p = v; }

// split fp32 -> bf16 hi + bf16 lo  (hi = RNE(x); lo = RNE(x - hi))
__device__ __forceinline__ void splitf(float x, u16& h, u16& l){
  u32 u = __float_as_uint(x);
  u32 hu = (u + (0x7FFFu + ((u >> 16) & 1u))) >> 16;
  h = (u16)hu;
  float hf = __uint_as_float(hu << 16);
  float r = x - hf;
  u32 v = __float_as_uint(r);
  v += 0x7FFFu + ((v >> 16) & 1u);
  l = (u16)(v >> 16);
}

__device__ __forceinline__ u32 packf(float x){
  u16 h,l; splitf(x,h,l);
  return (u32)h | ((u32)l << 16);
}

// ---------------- positional embedding ----------------
__global__ void pos_kernel(float* __restrict__ pos){
  int s = blockIdx.x, d = threadIdx.x;
  int row = s >> 5, col = s & 31;
  float base = (d < 128) ? (float)(row + 1) : (float)(col + 1);
  float val = base / (32.0f + 1e-6f) * 6.2831853071795864f;
  int dd = (d < 128) ? d : d - 128;
  int mf = dd >> 1;
  float f = powf(10000.0f, (float)mf * (1.0f/64.0f));
  float a = val / f;
  pos[s*DM + d] = (dd & 1) ? cosf(a) : sinf(a);
}

// ---------------- transposes ----------------
__global__ void tin_kernel(const float* __restrict__ x, float* __restrict__ tok){
  int idx = blockIdx.x*256 + threadIdx.x;
  if (idx >= NTOK*NCIN) return;
  int c = idx % NCIN;
  int n = idx / NCIN;
  int s = n >> 2, b = n & 3;
  tok[idx] = x[((long)(b*NCIN + c))*NHW + s];
}
__global__ void tout_kernel(const float* __restrict__ rec, float* __restrict__ out){
  int idx = blockIdx.x*256 + threadIdx.x;
  if (idx >= NTOK*NCIN) return;
  int s = idx & (NHW-1);
  int bc = idx >> 10;
  int b = bc / NCIN, c = bc % NCIN;
  out[idx] = rec[((long)(s*NB + b))*NCIN + c];
}

// -------- weight transpose+split: in [K][N] fp32 -> hi/lo planes [N][K] bf16 --------
__global__ __launch_bounds__(256) void tconv_kernel(const float* __restrict__ in,
    u16* __restrict__ oh, u16* __restrict__ ol, int K, int N){
  __shared__ float tile[32][33];
  long base = (long)blockIdx.z * (long)K * (long)N;
  int k0 = blockIdx.y*32, n0 = blockIdx.x*32;
  int tx = threadIdx.x & 31, ty = threadIdx.x >> 5;   // ty 0..7
  #pragma unroll
  for (int i=0;i<32;i+=8)
    tile[ty+i][tx] = in[base + (long)(k0+ty+i)*N + n0+tx];
  __syncthreads();
  #pragma unroll
  for (int i=0;i<32;i+=8){
    float v = tile[tx][ty+i];
    u16 h,l; splitf(v,h,l);
    long o = base + (long)(n0+ty+i)*K + k0+tx;
    oh[o]=h; ol[o]=l;
  }
}

// -------- elementwise split (no transpose): [N][K] fp32 -> hi/lo planes --------
__global__ void wsplit_kernel(const float* __restrict__ in, u16* __restrict__ oh,
    u16* __restrict__ ol, int n){
  int i = blockIdx.x*256 + threadIdx.x;
  if (i < n){ u16 h,l; splitf(in[i],h,l); oh[i]=h; ol[i]=l; }
}

// ---------------- split-bf16 MFMA GEMM body (3-term, depth-1 reg-prefetch) ----------------
// ASRC 0: A fp32. 1: A packed hi|lo u32. 2: A fp32 + pos[n>>2]. 3: A fp32 s-indexed + pos.
// ASRC 5: A = split-KV attention partials (O0+O1)*1/(l0+l1) fused merge; Av=OpB, pos=lB.
// CDST 0: C fp32. 1: C packed u32 pairs. 2: C fp32 scattered to row jmap[r], scaled by sflat.
template<bool GROUPED, bool INDIRECT, int ASRC, bool RELU, int CDST, int BK>
__device__ __forceinline__ void sgemm_body(
    const void* __restrict__ Av, int lda,
    const float* __restrict__ pos,
    const u16* __restrict__ Bhp, const u16* __restrict__ Blp, int ldb,
    const float* __restrict__ bias,
    void* __restrict__ Cv, int ldc,
    int M, int N, int K,
    const int* __restrict__ map,
    const int* __restrict__ cnt,
    const int* __restrict__ offs,
    const int* __restrict__ jmap,
    const float* __restrict__ sflat,
    long strideB, int strideBias, int e)
{
  constexpr int BM = 32;
  constexpr int NSEG = BK/32;
  constexpr int SW = (BK==32) ? 56 : 72;   // LDS row stride in u16 (16B aligned)
  int rows = GROUPED ? cnt[e] : M;
  int bn = blockIdx.x, bm = blockIdx.y;    // bn fastest: A-sharing blocks adjacent (L2)
  if (bm*BM >= rows) return;
  int row0 = GROUPED ? offs[e] : 0;
  const float* Af = (const float*)Av;
  const u32*   Ap = (const u32*)Av;
  if (GROUPED){ Bhp += (long)e*strideB; Blp += (long)e*strideB; }
  const float* biasp = bias ? (GROUPED ? bias + (long)e*strideBias : bias) : nullptr;

  extern __shared__ u16 smem[];
  u16* Ah = smem;                 // BM*SW
  u16* Al = Ah + BM*SW;
  u16* Bh = Al + BM*SW;           // 64*SW
  u16* Bl = Bh + 64*SW;

  int tid = threadIdx.x;
  int w = tid >> 6, ln = tid & 63;
  int wm = w >> 1, wn = w & 1;
  int lr = ln & 15, lh = ln >> 4;
  int srow = tid >> 2, sseg = tid & 3;

  int bgrow = bn*64 + srow;
  bool bok = bgrow < N;
  int agrow = bm*BM + srow;
  bool aok = (tid < BM*4) && (agrow < rows);
  long arow = 0;
  if (aok) arow = INDIRECT ? (long)map[row0 + agrow] : (long)(row0 + agrow);

  const f32x4 z4 = {0.f,0.f,0.f,0.f};
  f32x4 acc0 = z4, acc1 = z4;
  const s16x8 z8 = {0,0,0,0,0,0,0,0};

  s16x8 rBh[NSEG], rBl[NSEG];
  uint4 rA0[NSEG], rA1[NSEG];
  float4 rP0[NSEG], rP1[NSEG];
  float rinv[NSEG];

  auto load_stage = [&](int k0){
    #pragma unroll
    for (int s=0; s<NSEG; s++){
      int kk = k0 + s*32 + sseg*8;
      bool kok = kk < K;               // K % 8 == 0 always
      rBh[s] = z8; rBl[s] = z8;
      if (bok && kok){
        rBh[s] = *(const s16x8*)&Bhp[(long)bgrow*ldb + kk];
        rBl[s] = *(const s16x8*)&Blp[(long)bgrow*ldb + kk];
      }
      if (tid < BM*4){
        rA0[s] = make_uint4(0,0,0,0); rA1[s] = make_uint4(0,0,0,0);
        if (ASRC==2 || ASRC==3 || ASRC==5){
          rP0[s] = make_float4(0.f,0.f,0.f,0.f); rP1[s] = rP0[s]; rinv[s] = 0.f;
        }
        if (aok && kok){
          if (ASRC == 1){
            rA0[s] = *(const uint4*)&Ap[arow*lda + kk];
            rA1[s] = *(const uint4*)&Ap[arow*lda + kk + 4];
          } else if (ASRC == 5){
            long aoff = arow*(long)lda + kk;
            rA0[s] = *(const uint4*)&Af[aoff];                 // O0 [kk..kk+3]
            rA1[s] = *(const uint4*)&Af[aoff + 4];             // O0 [kk+4..kk+7]
            rP0[s] = ld4(&Af[(long)NTOK*DM + aoff]);           // O1 [kk..kk+3]
            rP1[s] = ld4(&Af[(long)NTOK*DM + aoff + 4]);       // O1 [kk+4..kk+7]
            int h = kk >> 5;                                   // head of this 8-chunk
            float l0 = pos[arow*8 + h];
            float l1 = pos[65536 + arow*8 + h];
            rinv[s] = 1.f / (l0 + l1);
          } else {
            long aoff = (ASRC==3 ? (long)(arow>>2) : arow)*lda + kk;
            rA0[s] = *(const uint4*)&Af[aoff];
            rA1[s] = *(const uint4*)&Af[aoff + 4];
            if (ASRC==2 || ASRC==3){
              long poff = (long)(arow>>2)*DM + kk;
              rP0[s] = ld4(&pos[poff]);
              rP1[s] = ld4(&pos[poff + 4]);
            }
          }
        }
      }
    }
  };

  auto write_stage = [&](){
    #pragma unroll
    for (int s=0; s<NSEG; s++){
      *(s16x8*)&Bh[srow*SW + s*32 + sseg*8] = rBh[s];
      *(s16x8*)&Bl[srow*SW + s*32 + sseg*8] = rBl[s];
      if (tid < BM*4){
        s16x8 hv, lv;
        if (ASRC == 1){
          u32 ws[8] = {rA0[s].x,rA0[s].y,rA0[s].z,rA0[s].w,rA1[s].x,rA1[s].y,rA1[s].z,rA1[s].w};
          #pragma unroll
          for (int t=0;t<8;t++){ hv[t]=(short)(ws[t]&0xFFFFu); lv[t]=(short)(ws[t]>>16); }
        } else {
          float xs[8] = {__uint_as_float(rA0[s].x),__uint_as_float(rA0[s].y),
                         __uint_as_float(rA0[s].z),__uint_as_float(rA0[s].w),
                         __uint_as_float(rA1[s].x),__uint_as_float(rA1[s].y),
                         __uint_as_float(rA1[s].z),__uint_as_float(rA1[s].w)};
          if (ASRC==2 || ASRC==3){
            xs[0]+=rP0[s].x; xs[1]+=rP0[s].y; xs[2]+=rP0[s].z; xs[3]+=rP0[s].w;
            xs[4]+=rP1[s].x; xs[5]+=rP1[s].y; xs[6]+=rP1[s].z; xs[7]+=rP1[s].w;
          }
          if (ASRC==5){
            float iv = rinv[s];
            xs[0]=(xs[0]+rP0[s].x)*iv; xs[1]=(xs[1]+rP0[s].y)*iv;
            xs[2]=(xs[2]+rP0[s].z)*iv; xs[3]=(xs[3]+rP0[s].w)*iv;
            xs[4]=(xs[4]+rP1[s].x)*iv; xs[5]=(xs[5]+rP1[s].y)*iv;
            xs[6]=(xs[6]+rP1[s].z)*iv; xs[7]=(xs[7]+rP1[s].w)*iv;
          }
          #pragma unroll
          for (int t=0;t<8;t++){ u16 hh,ll; splitf(xs[t],hh,ll); hv[t]=(short)hh; lv[t]=(short)ll; }
        }
        *(s16x8*)&Ah[srow*SW + s*32 + sseg*8] = hv;
        *(s16x8*)&Al[srow*SW + s*32 + sseg*8] = lv;
      }
    }
  };

  load_stage(0);
  for (int k0 = 0; k0 < K; k0 += BK){
    write_stage();
    __syncthreads();
    if (k0 + BK < K) load_stage(k0 + BK);   // loads fly across the MFMA phase + barriers
    #pragma unroll
    for (int s=0; s<NSEG; s++){
      int co = s*32 + lh*8;
      s16x8 a0h = *(const s16x8*)&Ah[(wm*16 + lr)*SW + co];
      s16x8 a0l = *(const s16x8*)&Al[(wm*16 + lr)*SW + co];
      s16x8 b0h = *(const s16x8*)&Bh[(wn*32      + lr)*SW + co];
      s16x8 b1h = *(const s16x8*)&Bh[(wn*32 + 16 + lr)*SW + co];
      s16x8 b0l = *(const s16x8*)&Bl[(wn*32      + lr)*SW + co];
      s16x8 b1l = *(const s16x8*)&Bl[(wn*32 + 16 + lr)*SW + co];
      acc0 = __builtin_amdgcn_mfma_f32_16x16x32_bf16(a0h, b0h, acc0, 0,0,0);
      acc1 = __builtin_amdgcn_mfma_f32_16x16x32_bf16(a0h, b1h, acc1, 0,0,0);
      acc0 = __builtin_amdgcn_mfma_f32_16x16x32_bf16(a0h, b0l, acc0, 0,0,0);
      acc1 = __builtin_amdgcn_mfma_f32_16x16x32_bf16(a0h, b1l, acc1, 0,0,0);
      acc0 = __builtin_amdgcn_mfma_f32_16x16x32_bf16(a0l, b0h, acc0, 0,0,0);
      acc1 = __builtin_amdgcn_mfma_f32_16x16x32_bf16(a0l, b1h, acc1, 0,0,0);
    }
    __syncthreads();
  }

  int c0 = bn*64 + wn*32 + lr;
  int c1 = c0 + 16;
  float bv0 = (biasp && c0 < N) ? biasp[c0] : 0.f;
  float bv1 = (biasp && c1 < N) ? biasp[c1] : 0.f;
  int rbase = bm*BM + wm*16 + lh*4;
  auto stc = [&](int gr, int gc, float vv){
    if (gr < rows && gc < N){
      float t = RELU ? fmaxf(vv, 0.f) : vv;
      if (CDST == 1){
        ((u32*)Cv)[(long)(row0+gr)*ldc + gc] = packf(t);
      } else if (CDST == 2){
        int ts = jmap[row0+gr];
        ((float*)Cv)[(long)ts*ldc + gc] = t * sflat[ts];
      } else {
        ((float*)Cv)[(long)(row0+gr)*ldc + gc] = t;
      }
    }
  };
  #pragma unroll
  for (int r = 0; r < 4; r++){
    stc(rbase + r, c0, acc0[r] + bv0);
    stc(rbase + r, c1, acc1[r] + bv1);
  }
}

// ---- named GEMM wrappers (dense K=256/272 GEMMs use BK=64: grids 2-6 blk/CU < 5/CU LDS cap) ----
__global__ __launch_bounds__(256) void gemm_in(const float* A, const u16* Bh_, const u16* Bl_,
    const float* bias, float* C){
  sgemm_body<false,false,0,false,0,64>(A, NCIN, nullptr, Bh_, Bl_, NCIN, bias, C, DM,
      NTOK, DM, NCIN, nullptr, nullptr, nullptr, nullptr, nullptr, 0, 0, 0);
}

__global__ __launch_bounds__(256) void gemm_out_k(const float* A, const u16* Bh_, const u16* Bl_,
    const float* bias, float* C){
  sgemm_body<false,false,0,false,0,64>(A, DM, nullptr, Bh_, Bl_, DM, bias, C, NCIN,
      NTOK, NCIN, DM, nullptr, nullptr, nullptr, nullptr, nullptr, 0, 0, 0);
}

// wos/woc: A = split-KV attention partials, merge fused into staging (ASRC=5)
__global__ __launch_bounds__(256) void gemm_wos(const float* OpB, const float* lB,
    const u16* Bh_, const u16* Bl_, const float* bias, float* C){
  sgemm_body<false,false,5,false,0,64>(OpB, DM, lB, Bh_, Bl_, DM, bias, C, DM,
      NTOK, DM, DM, nullptr, nullptr, nullptr, nullptr, nullptr, 0, 0, 0);
}

__global__ __launch_bounds__(256) void gemm_woc(const float* OpB, const float* lB,
    const u16* Bh_, const u16* Bl_, const float* bias, float* C){
  sgemm_body<false,false,5,false,0,64>(OpB, DM, lB, Bh_, Bl_, DM, bias, C, DM,
      NTOK, DM, DM, nullptr, nullptr, nullptr, nullptr, nullptr, 0, 0, 0);
}

template<int MQ, int MK>
__device__ __forceinline__ void qkv_body(const float* Aq, const float* Ak, const float* Avv,
    const float* pos, const u16* Bwh, const u16* Bwl, const float* bias,
    u32* Cq, u32* Ck, u32* Cvv){
  int z = blockIdx.z;
  const float* A = z==0 ? Aq : (z==1 ? Ak : Avv);
  u32* C = z==0 ? Cq : (z==1 ? Ck : Cvv);
  const u16* Bph = Bwh + (long)z*256*DM;
  const u16* Bpl = Bwl + (long)z*256*DM;
  const float* bp = bias + z*256;
  int mode = z==0 ? MQ : (z==1 ? MK : 0);
  if (mode == 3)
    sgemm_body<false,false,3,false,1,64>(A, DM, pos, Bph, Bpl, DM, bp, C, DM,
        NTOK, DM, DM, nullptr, nullptr, nullptr, nullptr, nullptr, 0, 0, 0);
  else if (mode == 2)
    sgemm_body<false,false,2,false,1,64>(A, DM, pos, Bph, Bpl, DM, bp, C, DM,
        NTOK, DM, DM, nullptr, nullptr, nullptr, nullptr, nullptr, 0, 0, 0);
  else
    sgemm_body<false,false,0,false,1,64>(A, DM, pos, Bph, Bpl, DM, bp, C, DM,
        NTOK, DM, DM, nullptr, nullptr, nullptr, nullptr, nullptr, 0, 0, 0);
}

__global__ __launch_bounds__(256) void gemm_qkv_s(const float* Aq, const float* Ak,
    const float* Avv, const float* pos, const u16* Bwh, const u16* Bwl, const float* bias,
    u32* Cq, u32* Ck, u32* Cvv){
  qkv_body<3,2>(Aq, Ak, Avv, pos, Bwh, Bwl, bias, Cq, Ck, Cvv);
}
__global__ __launch_bounds__(256) void gemm_qkv_c(const float* Aq, const float* Ak,
    const float* Avv, const float* pos, const u16* Bwh, const u16* Bwl, const float* bias,
    u32* Cq, u32* Ck, u32* Cvv){
  qkv_body<2,2>(Aq, Ak, Avv, pos, Bwh, Bwl, bias, Cq, Ck, Cvv);
}

// m1: 16 blk/CU grid -> LDS-capped; BK=32 keeps 7 blk/CU (vs 5 at BK=64)
__global__ __launch_bounds__(256) void gemm_m1(const float* A, const u16* Bh_, const u16* Bl_,
    const float* bias, u32* C, const int* map, const int* cnt, const int* offs){
  sgemm_body<true,true,0,true,1,32>(A, DM, nullptr, Bh_, Bl_, DM, bias, C, NDFF,
      0, NDFF, DM, map, cnt, offs, nullptr, nullptr, 262144L, NDFF, blockIdx.z);
}

__global__ __launch_bounds__(256) void gemm_m2(const u32* A, const u16* Bh_, const u16* Bl_,
    const float* bias, float* C, const int* cnt, const int* offs,
    const int* jmap, const float* sflat){
  sgemm_body<true,false,1,false,2,64>(A, NDFF, nullptr, Bh_, Bl_, NDFF, bias, C, DM,
      0, DM, NDFF, nullptr, cnt, offs, jmap, sflat, 262144L, DM, blockIdx.z);
}

// ---------------- MFMA flash attention, split-bf16, dh=32, SPLIT-KV ----------------
// Bounded-score softmax (no max-shift; logits provably small for this model).
__global__ __launch_bounds__(256) void attn_mfma(const u32* __restrict__ Q,
    const u32* __restrict__ Kb, const u32* __restrict__ Vb,
    float* __restrict__ OpBase, float* __restrict__ lBase)
{
  __shared__ u16 Kh[64*40], Kl[64*40];
  __shared__ u16 Vh[32*72], Vl[32*72];
  __shared__ u16 Ph[4][16*72], Pl[4][16*72];

  int qt = blockIdx.x, bh = blockIdx.y, z = blockIdx.z;
  int b = bh >> 3, h = bh & 7;
  int tid = threadIdx.x;
  int wv = tid >> 6, ln = tid & 63;
  int lr = ln & 15, lh = ln >> 4;
  const float scale = 0.17677669529663687f;  // 1/sqrt(32)
  int kt0 = z*8, kt1 = z*8 + 8;
  float* Op   = OpBase + (long)z*NTOK*DM;
  float* lArr = lBase + (long)z*65536;

  s16x8 qh, ql;
  {
    long qrow = ((long)((qt*64 + wv*16 + lr)*NB + b))*DM + h*32 + lh*8;
    uint4 p0 = *(const uint4*)&Q[qrow];
    uint4 p1 = *(const uint4*)&Q[qrow + 4];
    u32 ws[8] = {p0.x,p0.y,p0.z,p0.w,p1.x,p1.y,p1.z,p1.w};
    #pragma unroll
    for (int t=0;t<8;t++){ qh[t]=(short)(ws[t]&0xFFFFu); ql[t]=(short)(ws[t]>>16); }
  }

  int skey = tid >> 2, soct = tid & 3;
  int vkey0 = tid >> 3,        vd0 = (tid & 7) << 2;
  int vkey1 = (tid + 256) >> 3, vd1 = ((tid + 256) & 7) << 2;

  uint4 rK0, rK1, rV0, rV1;

  auto load_kv = [&](int kt){
    long gk = ((long)((kt*64 + skey)*NB + b))*DM + h*32 + soct*8;
    rK0 = *(const uint4*)&Kb[gk];
    rK1 = *(const uint4*)&Kb[gk + 4];
    rV0 = *(const uint4*)&Vb[((long)((kt*64 + vkey0)*NB + b))*DM + h*32 + vd0];
    rV1 = *(const uint4*)&Vb[((long)((kt*64 + vkey1)*NB + b))*DM + h*32 + vd1];
  };

  auto write_kv = [&](){
    u32 ws[8] = {rK0.x,rK0.y,rK0.z,rK0.w,rK1.x,rK1.y,rK1.z,rK1.w};
    s16x8 hv, lv;
    #pragma unroll
    for (int t=0;t<8;t++){ hv[t]=(short)(ws[t]&0xFFFFu); lv[t]=(short)(ws[t]>>16); }
    *(s16x8*)&Kh[skey*40 + soct*8] = hv;
    *(s16x8*)&Kl[skey*40 + soct*8] = lv;
    u32 v0[4] = {rV0.x,rV0.y,rV0.z,rV0.w};
    u32 v1[4] = {rV1.x,rV1.y,rV1.z,rV1.w};
    #pragma unroll
    for (int t=0;t<4;t++){
      Vh[(vd0+t)*72 + vkey0] = (u16)(v0[t]&0xFFFFu);
      Vl[(vd0+t)*72 + vkey0] = (u16)(v0[t]>>16);
      Vh[(vd1+t)*72 + vkey1] = (u16)(v1[t]&0xFFFFu);
      Vl[(vd1+t)*72 + vkey1] = (u16)(v1[t]>>16);
    }
  };

  const f32x4 z4 = {0.f,0.f,0.f,0.f};
  f32x4 oacc0 = z4, oacc1 = z4;
  float lp[4] = {0.f,0.f,0.f,0.f};

  load_kv(kt0);
  for (int kt = kt0; kt < kt1; kt++){
    write_kv();
    __syncthreads();
    if (kt + 1 < kt1) load_kv(kt + 1);

    #pragma unroll
    for (int s16t=0; s16t<4; s16t++){
      s16x8 kbh = *(const s16x8*)&Kh[(s16t*16 + lr)*40 + lh*8];
      s16x8 kbl = *(const s16x8*)&Kl[(s16t*16 + lr)*40 + lh*8];
      f32x4 a = z4;
      a = __builtin_amdgcn_mfma_f32_16x16x32_bf16(qh, kbh, a, 0,0,0);
      a = __builtin_amdgcn_mfma_f32_16x16x32_bf16(qh, kbl, a, 0,0,0);
      a = __builtin_amdgcn_mfma_f32_16x16x32_bf16(ql, kbh, a, 0,0,0);
      #pragma unroll
      for (int r=0;r<4;r++){
        float p = __expf(a[r]*scale);     // no max-shift: scores bounded
        lp[r] += p;
        u16 hh,ll; splitf(p,hh,ll);
        int off = (lh*4 + r)*72 + s16t*16 + lr;
        Ph[wv][off] = hh;
        Pl[wv][off] = ll;
      }
    }
    #pragma unroll
    for (int ks=0; ks<2; ks++){
      s16x8 pah = *(const s16x8*)&Ph[wv][lr*72 + ks*32 + lh*8];
      s16x8 pal = *(const s16x8*)&Pl[wv][lr*72 + ks*32 + lh*8];
      s16x8 vh0 = *(const s16x8*)&Vh[lr*72      + ks*32 + lh*8];
      s16x8 vl0 = *(const s16x8*)&Vl[lr*72      + ks*32 + lh*8];
      s16x8 vh1 = *(const s16x8*)&Vh[(16+lr)*72 + ks*32 + lh*8];
      s16x8 vl1 = *(const s16x8*)&Vl[(16+lr)*72 + ks*32 + lh*8];
      oacc0 = __builtin_amdgcn_mfma_f32_16x16x32_bf16(pah, vh0, oacc0, 0,0,0);
      oacc0 = __builtin_amdgcn_mfma_f32_16x16x32_bf16(pah, vl0, oacc0, 0,0,0);
      oacc0 = __builtin_amdgcn_mfma_f32_16x16x32_bf16(pal, vh0, oacc0, 0,0,0);
      oacc1 = __builtin_amdgcn_mfma_f32_16x16x32_bf16(pah, vh1, oacc1, 0,0,0);
      oacc1 = __builtin_amdgcn_mfma_f32_16x16x32_bf16(pah, vl1, oacc1, 0,0,0);
      oacc1 = __builtin_amdgcn_mfma_f32_16x16x32_bf16(pal, vh1, oacc1, 0,0,0);
    }
    __syncthreads();
  }
  #pragma unroll
  for (int mask=1; mask<=8; mask<<=1){
    #pragma unroll
    for (int r=0;r<4;r++) lp[r] += __shfl_xor(lp[r], mask);
  }
  #pragma unroll
  for (int r=0;r<4;r++){
    int q = qt*64 + wv*16 + lh*4 + r;
    long n = (long)q*NB + b;
    long orow = n*DM + h*32;
    Op[orow + lr]      = oacc0[r];
    Op[orow + 16 + lr] = oacc1[r];
    if (lr == 0) lArr[n*8 + h] = lp[r];
  }
}

// ---------------- LN / gate helpers ----------------
__device__ __forceinline__ float wave_sum(float v){
  #pragma unroll
  for (int m=1; m<64; m<<=1) v += __shfl_xor(v, m);
  return v;
}

__device__ __forceinline__ float4 ln_finish(float4 a, const float* g, const float* beta, int lane){
  float sum = wave_sum(a.x+a.y+a.z+a.w);
  float sq  = wave_sum(a.x*a.x + a.y*a.y + a.z*a.z + a.w*a.w);
  float mean = sum * (1.f/DM);
  float var  = sq * (1.f/DM) - mean*mean;
  float inv = 1.0f / sqrtf(var + 1e-5f);
  float4 gg = ld4(&g[lane*4]);
  float4 bb = ld4(&beta[lane*4]);
  float4 ov;
  ov.x = (a.x-mean)*inv*gg.x + bb.x;
  ov.y = (a.y-mean)*inv*gg.y + bb.y;
  ov.z = (a.z-mean)*inv*gg.z + bb.z;
  ov.w = (a.w-mean)*inv*gg.w + bb.w;
  return ov;
}

__device__ __forceinline__ void gate_from_regs(float4 ov, int row, int lane,
    const float* GW, const float* GB, float* scores, int* topi){
  float lg[8];
  #pragma unroll
  for (int e=0; e<8; e++){
    float4 wv = ld4(&GW[e*DM + lane*4]);
    lg[e] = ov.x*wv.x + ov.y*wv.y + ov.z*wv.z + ov.w*wv.w;
  }
  #pragma unroll
  for (int mask=1; mask<64; mask<<=1){
    #pragma unroll
    for (int e=0; e<8; e++) lg[e] += __shfl_xor(lg[e], mask);
  }
  #pragma unroll
  for (int e=0; e<8; e++) lg[e] += GB[e];
  int i0 = 0; float v0 = lg[0];
  #pragma unroll
  for (int e=1; e<8; e++) if (lg[e] > v0){ v0 = lg[e]; i0 = e; }
  int i1 = -1; float v1 = -1e30f;
  #pragma unroll
  for (int e=0; e<8; e++) if (e != i0 && lg[e] > v1){ v1 = lg[e]; i1 = e; }
  if (lane == 0){
    float ee = expf(v1 - v0);
    float inv = 1.f/(1.f + ee);
    scores[row*2]   = inv;
    scores[row*2+1] = ee*inv;
    topi[row*2]   = i0;
    topi[row*2+1] = i1;
  }
}

__global__ __launch_bounds__(256) void add_ln_le(const float* __restrict__ A,
    const float* __restrict__ Bv, const float* __restrict__ g, const float* __restrict__ beta,
    float* __restrict__ out)
{
  int row = blockIdx.x*4 + (threadIdx.x >> 6);
  int lane = threadIdx.x & 63;
  float4 a = ld4(&A[(long)(row>>2)*DM + lane*4]);
  float4 b = ld4(&Bv[(long)row*DM + lane*4]);
  a.x+=b.x; a.y+=b.y; a.z+=b.z; a.w+=b.w;
  float4 ov = ln_finish(a, g, beta, lane);
  st4(&out[(long)row*DM + lane*4], ov);
}

__global__ __launch_bounds__(256) void add_ln_gate(const float* __restrict__ A,
    const float* __restrict__ Bv, const float* __restrict__ g, const float* __restrict__ beta,
    float* __restrict__ out, const float* __restrict__ GW, const float* __restrict__ GB,
    float* __restrict__ scores, int* __restrict__ topi)
{
  int row = blockIdx.x*4 + (threadIdx.x >> 6);
  int lane = threadIdx.x & 63;
  float4 a = ld4(&A[(long)row*DM + lane*4]);
  float4 b = ld4(&Bv[(long)row*DM + lane*4]);
  a.x+=b.x; a.y+=b.y; a.z+=b.z; a.w+=b.w;
  float4 ov = ln_finish(a, g, beta, lane);
  st4(&out[(long)row*DM + lane*4], ov);
  gate_from_regs(ov, row, lane, GW, GB, scores, topi);
}

__global__ __launch_bounds__(256) void moe_ln_gate_k(const float* __restrict__ base,
    const float* __restrict__ yt,
    const float* __restrict__ g, const float* __restrict__ beta, float* __restrict__ out,
    const float* __restrict__ GW, const float* __restrict__ GB,
    float* __restrict__ scores2, int* __restrict__ topi2)
{
  int row = blockIdx.x*4 + (threadIdx.x >> 6);
  int lane = threadIdx.x & 63;
  float4 a  = ld4(&base[(long)row*DM + lane*4]);
  float4 y0 = ld4(&yt[(long)(row*2)*DM + lane*4]);
  float4 y1 = ld4(&yt[(long)(row*2+1)*DM + lane*4]);
  a.x += y0.x + y1.x;
  a.y += y0.y + y1.y;
  a.z += y0.z + y1.z;
  a.w += y0.w + y1.w;
  float4 ov = ln_finish(a, g, beta, lane);
  st4(&out[(long)row*DM + lane*4], ov);
  gate_from_regs(ov, row, lane, GW, GB, scores2, topi2);
}

__global__ __launch_bounds__(256) void moe_ln_fin_k(const float* __restrict__ base,
    const float* __restrict__ yt,
    const float* __restrict__ g, const float* __restrict__ beta, float* __restrict__ out)
{
  int row = blockIdx.x*4 + (threadIdx.x >> 6);
  int lane = threadIdx.x & 63;
  float4 a  = ld4(&base[(long)row*DM + lane*4]);
  float4 y0 = ld4(&yt[(long)(row*2)*DM + lane*4]);
  float4 y1 = ld4(&yt[(long)(row*2+1)*DM + lane*4]);
  a.x += y0.x + y1.x;
  a.y += y0.y + y1.y;
  a.z += y0.z + y1.z;
  a.w += y0.w + y1.w;
  float4 ov = ln_finish(a, g, beta, lane);
  st4(&out[(long)row*DM + lane*4], ov);
}

__global__ void offs_assign(const int* __restrict__ topi, int* __restrict__ cnt_g,
    int* __restrict__ offs_g, int* __restrict__ map, int* __restrict__ jmap)
{
  __shared__ int hist[72];
  __shared__ int offs[8];
  __shared__ int c2[8];
  int tid = threadIdx.x;
  if (tid < 72) hist[tid] = 0;
  __syncthreads();
  for (int idx = tid; idx < 2*NTOK; idx += 256){
    int e = topi[idx];
    atomicAdd(&hist[e*9 + (tid & 7)], 1);
  }
  __syncthreads();
  if (tid == 0){
    int o = 0;
    #pragma unroll
    for (int e=0; e<8; e++){
      int c = 0;
      #pragma unroll
      for (int s=0; s<8; s++) c += hist[e*9 + s];
      cnt_g[e] = c;
      offs[e] = o;
      offs_g[e] = o;
      o += c;
      c2[e] = 0;
    }
  }
  __syncthreads();
  for (int n = tid; n < NTOK; n += 256){
    #pragma unroll
    for (int j=0; j<2; j++){
      int e = topi[n*2+j];
      int slot = atomicAdd(&c2[e], 1);
      int r = offs[e] + slot;
      map[r] = n;
      jmap[r] = n*2 + j;
    }
  }
}

// =================================================================
extern "C" void kernel_launch(void* const* d_in, const int* in_sizes, int n_in,
                              void* d_out, int out_size, void* d_ws, size_t ws_size,
                              hipStream_t stream)
{
  const float* x      = (const float*)d_in[0];
  const float* Wi     = (const float*)d_in[1];
  const float* bi     = (const float*)d_in[2];
  const float* le     = (const float*)d_in[3];
  const float* Wqkv_s = (const float*)d_in[4];
  const float* bqkv_s = (const float*)d_in[5];
  const float* Wo_s   = (const float*)d_in[6];
  const float* bo_s   = (const float*)d_in[7];
  const float* Wqkv_c = (const float*)d_in[8];
  const float* bqkv_c = (const float*)d_in[9];
  const float* Wo_c   = (const float*)d_in[10];
  const float* bo_c   = (const float*)d_in[11];
  const float* ln_g   = (const float*)d_in[12];
  const float* ln_b   = (const float*)d_in[13];
  const float* gw1    = (const float*)d_in[14];
  const float* gb1    = (const float*)d_in[15];
  const float* W1a    = (const float*)d_in[16];
  const float* b1a    = (const float*)d_in[17];
  const float* W2a    = (const float*)d_in[18];
  const float* b2a    = (const float*)d_in[19];
  const float* gw2    = (const float*)d_in[20];
  const float* gb2    = (const float*)d_in[21];
  const float* W1b    = (const float*)d_in[22];
  const float* b1b    = (const float*)d_in[23];
  const float* W2b    = (const float*)d_in[24];
  const float* b2b    = (const float*)d_in[25];
  const float* Wout   = (const float*)d_in[26];
  const float* bout   = (const float*)d_in[27];

  float* w = (float*)d_ws;
  const long SZ = 1048576;            // NTOK*DM
  float* pos  = w;                    // 262144
  float* src  = pos  + 262144;
  float* t2s  = src  + SZ;
  float* tgtA = t2s  + SZ;
  float* dec  = tgtA + SZ;
  float* od   = dec;                  // ALIAS: od and dec have disjoint live ranges
  float* od2  = dec  + SZ;
  float* yt   = od2  + SZ;            // 2,097,152 fp32
  float* scoresA = yt + 2097152;      // 8192
  float* scoresB = scoresA + 8192;    // 8192
  u16* wsp  = (u16*)(scoresB + 8192);
  u16* W1ah = wsp;             u16* W1al = wsp + 2097152;
  u16* W1bh = wsp + 4194304;   u16* W1bl = wsp + 6291456;
  u16* W2ah = wsp + 8388608;   u16* W2al = wsp + 10485760;
  u16* W2bh = wsp + 12582912;  u16* W2bl = wsp + 14680064;
  u16* dwp  = wsp + 16777216;
  u16* Wih   = dwp;            u16* Wil   = dwp + 69632;
  u16* Wqsh  = dwp + 139264;   u16* Wqsl  = dwp + 335872;
  u16* Wosh  = dwp + 532480;   u16* Wosl  = dwp + 598016;
  u16* Wqch  = dwp + 663552;   u16* Wqcl  = dwp + 860160;
  u16* Woch  = dwp + 1056768;  u16* Wocl  = dwp + 1122304;
  u16* Wouth = dwp + 1187840;  u16* Woutl = dwp + 1257472;
  // overlay region R: 8,388,608 floats
  float* R   = (float*)(dwp + 1327104);
  float* tok = R;                     // dead before q written
  u32*  q    = (u32*)R;               // packed pairs
  u32*  k    = (u32*)(R + SZ);        // packed; reused as t2c (fp32) after attn
  u32*  v    = (u32*)(R + 2*SZ);      // packed pairs
  float* OpB = R + 4*SZ;              // split-KV partial O: 2 x SZ fp32
  float* lB  = R + 6*SZ;              // l halves: 2 x 65536
  u32*  hg   = (u32*)R;               // MoE phase (q..Op dead)
  float* rec = R;                     // final
  int* ip    = (int*)(R + 8388608);
  int* topiA = ip;
  int* topiB = ip + 8192;
  int* map   = ip + 16384;
  int* jmapA = ip + 24576;
  int* jmapB = ip + 32768;
  int* cnts  = ip + 40960;
  int* offsg = ip + 40992;

  dim3 blk(256);
  dim3 gDense(4, 128, 1);
  dim3 gQKV(4, 128, 3);
  dim3 gMoe1(16, 128, 8);
  dim3 gMoe2(4, 128, 8);
  dim3 gAttn(16, 32, 2);

  pos_kernel<<<NHW, DM, 0, stream>>>(pos);
  tin_kernel<<<(NTOK*NCIN + 255)/256, blk, 0, stream>>>(x, tok);

  tconv_kernel<<<dim3(32, 8, 8), blk, 0, stream>>>(W1a, W1ah, W1al, DM,   NDFF);
  tconv_kernel<<<dim3(32, 8, 8), blk, 0, stream>>>(W1b, W1bh, W1bl, DM,   NDFF);
  tconv_kernel<<<dim3(8, 32, 8), blk, 0, stream>>>(W2a, W2ah, W2al, NDFF, DM);
  tconv_kernel<<<dim3(8, 32, 8), blk, 0, stream>>>(W2b, W2bh, W2bl, NDFF, DM);
  wsplit_kernel<<<272, blk, 0, stream>>>(Wi,     Wih,   Wil,   69632);
  wsplit_kernel<<<768, blk, 0, stream>>>(Wqkv_s, Wqsh,  Wqsl,  196608);
  wsplit_kernel<<<256, blk, 0, stream>>>(Wo_s,   Wosh,  Wosl,  65536);
  wsplit_kernel<<<768, blk, 0, stream>>>(Wqkv_c, Wqch,  Wqcl,  196608);
  wsplit_kernel<<<256, blk, 0, stream>>>(Wo_c,   Woch,  Wocl,  65536);
  wsplit_kernel<<<272, blk, 0, stream>>>(Wout,   Wouth, Woutl, 69632);

  gemm_in<<<gDense, blk, GEMM_SMEM64, stream>>>(tok, Wih, Wil, bi, src);

  gemm_qkv_s<<<gQKV, blk, GEMM_SMEM64, stream>>>(le, src, src, pos, Wqsh, Wqsl, bqkv_s, q, k, v);
  attn_mfma<<<gAttn, blk, 0, stream>>>(q, k, v, OpB, lB);
  gemm_wos<<<gDense, blk, GEMM_SMEM64, stream>>>(OpB, lB, Wosh, Wosl, bo_s, t2s);

  const float* decIn = src;
  for (int i = 0; i < 2; i++){
    int* cntA = cnts + (i*2)*8;   int* offsA = offsg + (i*2)*8;
    int* cntB = cnts + (i*2+1)*8; int* offsB = offsg + (i*2+1)*8;

    add_ln_le<<<1024, blk, 0, stream>>>(le, t2s, ln_g + (4*i)*DM, ln_b + (4*i)*DM, tgtA);
    gemm_qkv_c<<<gQKV, blk, GEMM_SMEM64, stream>>>(tgtA, decIn, decIn, pos, Wqch, Wqcl, bqkv_c, q, k, v);
    attn_mfma<<<gAttn, blk, 0, stream>>>(q, k, v, OpB, lB);
    gemm_woc<<<gDense, blk, GEMM_SMEM64, stream>>>(OpB, lB, Woch, Wocl, bo_c, (float*)k);
    add_ln_gate<<<1024, blk, 0, stream>>>(tgtA, (float*)k, ln_g + (4*i+1)*DM, ln_b + (4*i+1)*DM, od,
        gw1, gb1, scoresA, topiA);

    offs_assign<<<1, blk, 0, stream>>>(topiA, cntA, offsA, map, jmapA);
    gemm_m1<<<gMoe1, blk, GEMM_SMEM32, stream>>>(od, W1ah, W1al, b1a, hg, map, cntA, offsA);
    gemm_m2<<<gMoe2, blk, GEMM_SMEM64, stream>>>(hg, W2ah, W2al, b2a, yt, cntA, offsA,
        jmapA, scoresA);
    moe_ln_gate_k<<<1024, blk, 0, stream>>>(od, yt,
        ln_g + (4*i+2)*DM, ln_b + (4*i+2)*DM, od2, gw2, gb2, scoresB, topiB);

    offs_assign<<<1, blk, 0, stream>>>(topiB, cntB, offsB, map, jmapB);
    gemm_m1<<<gMoe1, blk, GEMM_SMEM32, stream>>>(od2, W1bh, W1bl, b1b, hg, map, cntB, offsB);
    gemm_m2<<<gMoe2, blk, GEMM_SMEM64, stream>>>(hg, W2bh, W2bl, b2b, yt, cntB, offsB,
        jmapB, scoresB);
    moe_ln_fin_k<<<1024, blk, 0, stream>>>(od2, yt,
        ln_g + (4*i+3)*DM, ln_b + (4*i+3)*DM, dec);

    decIn = dec;
  }

  gemm_out_k<<<dim3(5,128,1), blk, GEMM_SMEM64, stream>>>(dec, Wouth, Woutl, bout, rec);
  tout_kernel<<<(NTOK*NCIN + 255)/256, blk, 0, stream>>>(rec, (float*)d_out);
}

// Round 28
// 603.795 us; speedup vs baseline: 1.0702x; 1.0389x over previous
//
#include <hip/hip_runtime.h>

#define NHW 1024
#define NB 4
#define DM 256
#define NTOK 4096      // NHW * NB
#define NCIN 272
#define NDFF 1024

typedef unsigned short u16;
typedef unsigned int u32;
typedef __attribute__((ext_vector_type(8))) short s16x8;
typedef __attribute__((ext_vector_type(4))) float f32x4;

static const int GEMM_SMEM32 = (32+32+64+64)*56*2;   // 21504 B (BK=32)
static const int GEMM_SMEM64 = (32+32+64+64)*72*2;   // 27648 B (BK=64)

__device__ __forceinline__ float4 ld4(const float* p){ return *(const float4*)p; }
__device__ __forceinline__ void st4(float* p, float4 v){ *(float4*)p = v; }

// split fp32 -> bf16 hi + bf16 lo  (hi = RNE(x); lo = RNE(x - hi))
__device__ __forceinline__ void splitf(float x, u16& h, u16& l){
  u32 u = __float_as_uint(x);
  u32 hu = (u + (0x7FFFu + ((u >> 16) & 1u))) >> 16;
  h = (u16)hu;
  float hf = __uint_as_float(hu << 16);
  float r = x - hf;
  u32 v = __float_as_uint(r);
  v += 0x7FFFu + ((v >> 16) & 1u);
  l = (u16)(v >> 16);
}

__device__ __forceinline__ u32 packf(float x){
  u16 h,l; splitf(x,h,l);
  return (u32)h | ((u32)l << 16);
}

// ---------------- positional embedding ----------------
__global__ void pos_kernel(float* __restrict__ pos){
  int s = blockIdx.x, d = threadIdx.x;
  int row = s >> 5, col = s & 31;
  float base = (d < 128) ? (float)(row + 1) : (float)(col + 1);
  float val = base / (32.0f + 1e-6f) * 6.2831853071795864f;
  int dd = (d < 128) ? d : d - 128;
  int mf = dd >> 1;
  float f = powf(10000.0f, (float)mf * (1.0f/64.0f));
  float a = val / f;
  pos[s*DM + d] = (dd & 1) ? cosf(a) : sinf(a);
}

// ---------------- transposes ----------------
__global__ void tin_kernel(const float* __restrict__ x, float* __restrict__ tok){
  int idx = blockIdx.x*256 + threadIdx.x;
  if (idx >= NTOK*NCIN) return;
  int c = idx % NCIN;
  int n = idx / NCIN;
  int s = n >> 2, b = n & 3;
  tok[idx] = x[((long)(b*NCIN + c))*NHW + s];
}
__global__ void tout_kernel(const float* __restrict__ rec, float* __restrict__ out){
  int idx = blockIdx.x*256 + threadIdx.x;
  if (idx >= NTOK*NCIN) return;
  int s = idx & (NHW-1);
  int bc = idx >> 10;
  int b = bc / NCIN, c = bc % NCIN;
  out[idx] = rec[((long)(s*NB + b))*NCIN + c];
}

// -------- weight transpose+split (2 tensors per launch): [K][N] fp32 -> [N][K] hi/lo --------
// blockIdx.z in 0..15: sel = z>>3 picks tensor, zz = z&7 is the expert slice.
__global__ __launch_bounds__(256) void tconv2_kernel(
    const float* __restrict__ in0, u16* __restrict__ oh0, u16* __restrict__ ol0,
    const float* __restrict__ in1, u16* __restrict__ oh1, u16* __restrict__ ol1,
    int K, int N){
  __shared__ float tile[32][33];
  int sel = blockIdx.z >> 3, zz = blockIdx.z & 7;
  const float* in = sel ? in1 : in0;
  u16* oh = sel ? oh1 : oh0;
  u16* ol = sel ? ol1 : ol0;
  long base = (long)zz * (long)K * (long)N;
  int k0 = blockIdx.y*32, n0 = blockIdx.x*32;
  int tx = threadIdx.x & 31, ty = threadIdx.x >> 5;   // ty 0..7
  #pragma unroll
  for (int i=0;i<32;i+=8)
    tile[ty+i][tx] = in[base + (long)(k0+ty+i)*N + n0+tx];
  __syncthreads();
  #pragma unroll
  for (int i=0;i<32;i+=8){
    float v = tile[tx][ty+i];
    u16 h,l; splitf(v,h,l);
    long o = base + (long)(n0+ty+i)*K + k0+tx;
    oh[o]=h; ol[o]=l;
  }
}

// -------- elementwise split, 6 tensors in one launch (z selects) --------
__global__ void wsplit6_kernel(
    const float* __restrict__ s0, u16* __restrict__ h0, u16* __restrict__ l0, int n0,
    const float* __restrict__ s1, u16* __restrict__ h1, u16* __restrict__ l1, int n1,
    const float* __restrict__ s2, u16* __restrict__ h2, u16* __restrict__ l2, int n2,
    const float* __restrict__ s3, u16* __restrict__ h3, u16* __restrict__ l3, int n3,
    const float* __restrict__ s4, u16* __restrict__ h4, u16* __restrict__ l4, int n4,
    const float* __restrict__ s5, u16* __restrict__ h5, u16* __restrict__ l5, int n5){
  int z = blockIdx.z;
  const float* in; u16* oh; u16* ol; int n;
  switch(z){
    case 0: in=s0; oh=h0; ol=l0; n=n0; break;
    case 1: in=s1; oh=h1; ol=l1; n=n1; break;
    case 2: in=s2; oh=h2; ol=l2; n=n2; break;
    case 3: in=s3; oh=h3; ol=l3; n=n3; break;
    case 4: in=s4; oh=h4; ol=l4; n=n4; break;
    default:in=s5; oh=h5; ol=l5; n=n5; break;
  }
  int i = blockIdx.x*256 + threadIdx.x;
  if (i < n){ u16 h,l; splitf(in[i],h,l); oh[i]=h; ol[i]=l; }
}

// ---------------- split-bf16 MFMA GEMM body (3-term, depth-1 reg-prefetch) ----------------
// ASRC 0: A fp32. 1: A packed hi|lo u32. 2: A fp32 + pos[n>>2]. 3: A fp32 s-indexed + pos.
// ASRC 5: A = split-KV attention partials (O0+O1)*1/(l0+l1) fused merge; Av=OpB, pos=lB.
// CDST 0: C fp32. 1: C packed u32 pairs. 2: C fp32 scattered to row jmap[r], scaled by sflat.
template<bool GROUPED, bool INDIRECT, int ASRC, bool RELU, int CDST, int BK>
__device__ __forceinline__ void sgemm_body(
    const void* __restrict__ Av, int lda,
    const float* __restrict__ pos,
    const u16* __restrict__ Bhp, const u16* __restrict__ Blp, int ldb,
    const float* __restrict__ bias,
    void* __restrict__ Cv, int ldc,
    int M, int N, int K,
    const int* __restrict__ map,
    const int* __restrict__ cnt,
    const int* __restrict__ offs,
    const int* __restrict__ jmap,
    const float* __restrict__ sflat,
    long strideB, int strideBias, int e)
{
  constexpr int BM = 32;
  constexpr int NSEG = BK/32;
  constexpr int SW = (BK==32) ? 56 : 72;   // LDS row stride in u16 (16B aligned)
  int rows = GROUPED ? cnt[e] : M;
  int bn = blockIdx.x, bm = blockIdx.y;    // bn fastest: A-sharing blocks adjacent (L2)
  if (bm*BM >= rows) return;
  int row0 = GROUPED ? offs[e] : 0;
  const float* Af = (const float*)Av;
  const u32*   Ap = (const u32*)Av;
  if (GROUPED){ Bhp += (long)e*strideB; Blp += (long)e*strideB; }
  const float* biasp = bias ? (GROUPED ? bias + (long)e*strideBias : bias) : nullptr;

  extern __shared__ u16 smem[];
  u16* Ah = smem;                 // BM*SW
  u16* Al = Ah + BM*SW;
  u16* Bh = Al + BM*SW;           // 64*SW
  u16* Bl = Bh + 64*SW;

  int tid = threadIdx.x;
  int w = tid >> 6, ln = tid & 63;
  int wm = w >> 1, wn = w & 1;
  int lr = ln & 15, lh = ln >> 4;
  int srow = tid >> 2, sseg = tid & 3;

  int bgrow = bn*64 + srow;
  bool bok = bgrow < N;
  int agrow = bm*BM + srow;
  bool aok = (tid < BM*4) && (agrow < rows);
  long arow = 0;
  if (aok) arow = INDIRECT ? (long)map[row0 + agrow] : (long)(row0 + agrow);

  const f32x4 z4 = {0.f,0.f,0.f,0.f};
  f32x4 acc0 = z4, acc1 = z4;
  const s16x8 z8 = {0,0,0,0,0,0,0,0};

  s16x8 rBh[NSEG], rBl[NSEG];
  uint4 rA0[NSEG], rA1[NSEG];
  float4 rP0[NSEG], rP1[NSEG];
  float rinv[NSEG];

  auto load_stage = [&](int k0){
    #pragma unroll
    for (int s=0; s<NSEG; s++){
      int kk = k0 + s*32 + sseg*8;
      bool kok = kk < K;               // K % 8 == 0 always
      rBh[s] = z8; rBl[s] = z8;
      if (bok && kok){
        rBh[s] = *(const s16x8*)&Bhp[(long)bgrow*ldb + kk];
        rBl[s] = *(const s16x8*)&Blp[(long)bgrow*ldb + kk];
      }
      if (tid < BM*4){
        rA0[s] = make_uint4(0,0,0,0); rA1[s] = make_uint4(0,0,0,0);
        if (ASRC==2 || ASRC==3 || ASRC==5){
          rP0[s] = make_float4(0.f,0.f,0.f,0.f); rP1[s] = rP0[s]; rinv[s] = 0.f;
        }
        if (aok && kok){
          if (ASRC == 1){
            rA0[s] = *(const uint4*)&Ap[arow*lda + kk];
            rA1[s] = *(const uint4*)&Ap[arow*lda + kk + 4];
          } else if (ASRC == 5){
            long aoff = arow*(long)lda + kk;
            rA0[s] = *(const uint4*)&Af[aoff];                 // O0 [kk..kk+3]
            rA1[s] = *(const uint4*)&Af[aoff + 4];             // O0 [kk+4..kk+7]
            rP0[s] = ld4(&Af[(long)NTOK*DM + aoff]);           // O1 [kk..kk+3]
            rP1[s] = ld4(&Af[(long)NTOK*DM + aoff + 4]);       // O1 [kk+4..kk+7]
            int h = kk >> 5;                                   // head of this 8-chunk
            float l0 = pos[arow*8 + h];
            float l1 = pos[65536 + arow*8 + h];
            rinv[s] = 1.f / (l0 + l1);
          } else {
            long aoff = (ASRC==3 ? (long)(arow>>2) : arow)*lda + kk;
            rA0[s] = *(const uint4*)&Af[aoff];
            rA1[s] = *(const uint4*)&Af[aoff + 4];
            if (ASRC==2 || ASRC==3){
              long poff = (long)(arow>>2)*DM + kk;
              rP0[s] = ld4(&pos[poff]);
              rP1[s] = ld4(&pos[poff + 4]);
            }
          }
        }
      }
    }
  };

  auto write_stage = [&](){
    #pragma unroll
    for (int s=0; s<NSEG; s++){
      *(s16x8*)&Bh[srow*SW + s*32 + sseg*8] = rBh[s];
      *(s16x8*)&Bl[srow*SW + s*32 + sseg*8] = rBl[s];
      if (tid < BM*4){
        s16x8 hv, lv;
        if (ASRC == 1){
          u32 ws[8] = {rA0[s].x,rA0[s].y,rA0[s].z,rA0[s].w,rA1[s].x,rA1[s].y,rA1[s].z,rA1[s].w};
          #pragma unroll
          for (int t=0;t<8;t++){ hv[t]=(short)(ws[t]&0xFFFFu); lv[t]=(short)(ws[t]>>16); }
        } else {
          float xs[8] = {__uint_as_float(rA0[s].x),__uint_as_float(rA0[s].y),
                         __uint_as_float(rA0[s].z),__uint_as_float(rA0[s].w),
                         __uint_as_float(rA1[s].x),__uint_as_float(rA1[s].y),
                         __uint_as_float(rA1[s].z),__uint_as_float(rA1[s].w)};
          if (ASRC==2 || ASRC==3){
            xs[0]+=rP0[s].x; xs[1]+=rP0[s].y; xs[2]+=rP0[s].z; xs[3]+=rP0[s].w;
            xs[4]+=rP1[s].x; xs[5]+=rP1[s].y; xs[6]+=rP1[s].z; xs[7]+=rP1[s].w;
          }
          if (ASRC==5){
            float iv = rinv[s];
            xs[0]=(xs[0]+rP0[s].x)*iv; xs[1]=(xs[1]+rP0[s].y)*iv;
            xs[2]=(xs[2]+rP0[s].z)*iv; xs[3]=(xs[3]+rP0[s].w)*iv;
            xs[4]=(xs[4]+rP1[s].x)*iv; xs[5]=(xs[5]+rP1[s].y)*iv;
            xs[6]=(xs[6]+rP1[s].z)*iv; xs[7]=(xs[7]+rP1[s].w)*iv;
          }
          #pragma unroll
          for (int t=0;t<8;t++){ u16 hh,ll; splitf(xs[t],hh,ll); hv[t]=(short)hh; lv[t]=(short)ll; }
        }
        *(s16x8*)&Ah[srow*SW + s*32 + sseg*8] = hv;
        *(s16x8*)&Al[srow*SW + s*32 + sseg*8] = lv;
      }
    }
  };

  load_stage(0);
  for (int k0 = 0; k0 < K; k0 += BK){
    write_stage();
    __syncthreads();
    if (k0 + BK < K) load_stage(k0 + BK);   // loads fly across the MFMA phase + barriers
    #pragma unroll
    for (int s=0; s<NSEG; s++){
      int co = s*32 + lh*8;
      s16x8 a0h = *(const s16x8*)&Ah[(wm*16 + lr)*SW + co];
      s16x8 a0l = *(const s16x8*)&Al[(wm*16 + lr)*SW + co];
      s16x8 b0h = *(const s16x8*)&Bh[(wn*32      + lr)*SW + co];
      s16x8 b1h = *(const s16x8*)&Bh[(wn*32 + 16 + lr)*SW + co];
      s16x8 b0l = *(const s16x8*)&Bl[(wn*32      + lr)*SW + co];
      s16x8 b1l = *(const s16x8*)&Bl[(wn*32 + 16 + lr)*SW + co];
      acc0 = __builtin_amdgcn_mfma_f32_16x16x32_bf16(a0h, b0h, acc0, 0,0,0);
      acc1 = __builtin_amdgcn_mfma_f32_16x16x32_bf16(a0h, b1h, acc1, 0,0,0);
      acc0 = __builtin_amdgcn_mfma_f32_16x16x32_bf16(a0h, b0l, acc0, 0,0,0);
      acc1 = __builtin_amdgcn_mfma_f32_16x16x32_bf16(a0h, b1l, acc1, 0,0,0);
      acc0 = __builtin_amdgcn_mfma_f32_16x16x32_bf16(a0l, b0h, acc0, 0,0,0);
      acc1 = __builtin_amdgcn_mfma_f32_16x16x32_bf16(a0l, b1h, acc1, 0,0,0);
    }
    __syncthreads();
  }

  int c0 = bn*64 + wn*32 + lr;
  int c1 = c0 + 16;
  float bv0 = (biasp && c0 < N) ? biasp[c0] : 0.f;
  float bv1 = (biasp && c1 < N) ? biasp[c1] : 0.f;
  int rbase = bm*BM + wm*16 + lh*4;
  auto stc = [&](int gr, int gc, float vv){
    if (gr < rows && gc < N){
      float t = RELU ? fmaxf(vv, 0.f) : vv;
      if (CDST == 1){
        ((u32*)Cv)[(long)(row0+gr)*ldc + gc] = packf(t);
      } else if (CDST == 2){
        int ts = jmap[row0+gr];
        ((float*)Cv)[(long)ts*ldc + gc] = t * sflat[ts];
      } else {
        ((float*)Cv)[(long)(row0+gr)*ldc + gc] = t;
      }
    }
  };
  #pragma unroll
  for (int r = 0; r < 4; r++){
    stc(rbase + r, c0, acc0[r] + bv0);
    stc(rbase + r, c1, acc1[r] + bv1);
  }
}

// ---- named GEMM wrappers (all BK=32 except m2: packed-A path tolerates deeper unroll) ----
__global__ __launch_bounds__(256) void gemm_in(const float* A, const u16* Bh_, const u16* Bl_,
    const float* bias, float* C){
  sgemm_body<false,false,0,false,0,32>(A, NCIN, nullptr, Bh_, Bl_, NCIN, bias, C, DM,
      NTOK, DM, NCIN, nullptr, nullptr, nullptr, nullptr, nullptr, 0, 0, 0);
}

__global__ __launch_bounds__(256) void gemm_out_k(const float* A, const u16* Bh_, const u16* Bl_,
    const float* bias, float* C){
  sgemm_body<false,false,0,false,0,32>(A, DM, nullptr, Bh_, Bl_, DM, bias, C, NCIN,
      NTOK, NCIN, DM, nullptr, nullptr, nullptr, nullptr, nullptr, 0, 0, 0);
}

// wos/woc: A = split-KV attention partials, merge fused into staging (ASRC=5)
__global__ __launch_bounds__(256) void gemm_wos(const float* OpB, const float* lB,
    const u16* Bh_, const u16* Bl_, const float* bias, float* C){
  sgemm_body<false,false,5,false,0,32>(OpB, DM, lB, Bh_, Bl_, DM, bias, C, DM,
      NTOK, DM, DM, nullptr, nullptr, nullptr, nullptr, nullptr, 0, 0, 0);
}

__global__ __launch_bounds__(256) void gemm_woc(const float* OpB, const float* lB,
    const u16* Bh_, const u16* Bl_, const float* bias, float* C){
  sgemm_body<false,false,5,false,0,32>(OpB, DM, lB, Bh_, Bl_, DM, bias, C, DM,
      NTOK, DM, DM, nullptr, nullptr, nullptr, nullptr, nullptr, 0, 0, 0);
}

template<int MQ, int MK>
__device__ __forceinline__ void qkv_body(const float* Aq, const float* Ak, const float* Avv,
    const float* pos, const u16* Bwh, const u16* Bwl, const float* bias,
    u32* Cq, u32* Ck, u32* Cvv){
  int z = blockIdx.z;
  const float* A = z==0 ? Aq : (z==1 ? Ak : Avv);
  u32* C = z==0 ? Cq : (z==1 ? Ck : Cvv);
  const u16* Bph = Bwh + (long)z*256*DM;
  const u16* Bpl = Bwl + (long)z*256*DM;
  const float* bp = bias + z*256;
  int mode = z==0 ? MQ : (z==1 ? MK : 0);
  if (mode == 3)
    sgemm_body<false,false,3,false,1,32>(A, DM, pos, Bph, Bpl, DM, bp, C, DM,
        NTOK, DM, DM, nullptr, nullptr, nullptr, nullptr, nullptr, 0, 0, 0);
  else if (mode == 2)
    sgemm_body<false,false,2,false,1,32>(A, DM, pos, Bph, Bpl, DM, bp, C, DM,
        NTOK, DM, DM, nullptr, nullptr, nullptr, nullptr, nullptr, 0, 0, 0);
  else
    sgemm_body<false,false,0,false,1,32>(A, DM, pos, Bph, Bpl, DM, bp, C, DM,
        NTOK, DM, DM, nullptr, nullptr, nullptr, nullptr, nullptr, 0, 0, 0);
}

__global__ __launch_bounds__(256) void gemm_qkv_s(const float* Aq, const float* Ak,
    const float* Avv, const float* pos, const u16* Bwh, const u16* Bwl, const float* bias,
    u32* Cq, u32* Ck, u32* Cvv){
  qkv_body<3,2>(Aq, Ak, Avv, pos, Bwh, Bwl, bias, Cq, Ck, Cvv);
}
__global__ __launch_bounds__(256) void gemm_qkv_c(const float* Aq, const float* Ak,
    const float* Avv, const float* pos, const u16* Bwh, const u16* Bwl, const float* bias,
    u32* Cq, u32* Ck, u32* Cvv){
  qkv_body<2,2>(Aq, Ak, Avv, pos, Bwh, Bwl, bias, Cq, Ck, Cvv);
}

__global__ __launch_bounds__(256) void gemm_m1(const float* A, const u16* Bh_, const u16* Bl_,
    const float* bias, u32* C, const int* map, const int* cnt, const int* offs){
  sgemm_body<true,true,0,true,1,32>(A, DM, nullptr, Bh_, Bl_, DM, bias, C, NDFF,
      0, NDFF, DM, map, cnt, offs, nullptr, nullptr, 262144L, NDFF, blockIdx.z);
}

__global__ __launch_bounds__(256) void gemm_m2(const u32* A, const u16* Bh_, const u16* Bl_,
    const float* bias, float* C, const int* cnt, const int* offs,
    const int* jmap, const float* sflat){
  sgemm_body<true,false,1,false,2,64>(A, NDFF, nullptr, Bh_, Bl_, NDFF, bias, C, DM,
      0, DM, NDFF, nullptr, cnt, offs, jmap, sflat, 262144L, DM, blockIdx.z);
}

// ---------------- MFMA flash attention, split-bf16, dh=32, SPLIT-KV ----------------
// Bounded-score softmax (no max-shift; logits provably small for this model).
__global__ __launch_bounds__(256) void attn_mfma(const u32* __restrict__ Q,
    const u32* __restrict__ Kb, const u32* __restrict__ Vb,
    float* __restrict__ OpBase, float* __restrict__ lBase)
{
  __shared__ u16 Kh[64*40], Kl[64*40];
  __shared__ u16 Vh[32*72], Vl[32*72];
  __shared__ u16 Ph[4][16*72], Pl[4][16*72];

  int qt = blockIdx.x, bh = blockIdx.y, z = blockIdx.z;
  int b = bh >> 3, h = bh & 7;
  int tid = threadIdx.x;
  int wv = tid >> 6, ln = tid & 63;
  int lr = ln & 15, lh = ln >> 4;
  const float scale = 0.17677669529663687f;  // 1/sqrt(32)
  int kt0 = z*8, kt1 = z*8 + 8;
  float* Op   = OpBase + (long)z*NTOK*DM;
  float* lArr = lBase + (long)z*65536;

  s16x8 qh, ql;
  {
    long qrow = ((long)((qt*64 + wv*16 + lr)*NB + b))*DM + h*32 + lh*8;
    uint4 p0 = *(const uint4*)&Q[qrow];
    uint4 p1 = *(const uint4*)&Q[qrow + 4];
    u32 ws[8] = {p0.x,p0.y,p0.z,p0.w,p1.x,p1.y,p1.z,p1.w};
    #pragma unroll
    for (int t=0;t<8;t++){ qh[t]=(short)(ws[t]&0xFFFFu); ql[t]=(short)(ws[t]>>16); }
  }

  int skey = tid >> 2, soct = tid & 3;
  int vkey0 = tid >> 3,        vd0 = (tid & 7) << 2;
  int vkey1 = (tid + 256) >> 3, vd1 = ((tid + 256) & 7) << 2;

  uint4 rK0, rK1, rV0, rV1;

  auto load_kv = [&](int kt){
    long gk = ((long)((kt*64 + skey)*NB + b))*DM + h*32 + soct*8;
    rK0 = *(const uint4*)&Kb[gk];
    rK1 = *(const uint4*)&Kb[gk + 4];
    rV0 = *(const uint4*)&Vb[((long)((kt*64 + vkey0)*NB + b))*DM + h*32 + vd0];
    rV1 = *(const uint4*)&Vb[((long)((kt*64 + vkey1)*NB + b))*DM + h*32 + vd1];
  };

  auto write_kv = [&](){
    u32 ws[8] = {rK0.x,rK0.y,rK0.z,rK0.w,rK1.x,rK1.y,rK1.z,rK1.w};
    s16x8 hv, lv;
    #pragma unroll
    for (int t=0;t<8;t++){ hv[t]=(short)(ws[t]&0xFFFFu); lv[t]=(short)(ws[t]>>16); }
    *(s16x8*)&Kh[skey*40 + soct*8] = hv;
    *(s16x8*)&Kl[skey*40 + soct*8] = lv;
    u32 v0[4] = {rV0.x,rV0.y,rV0.z,rV0.w};
    u32 v1[4] = {rV1.x,rV1.y,rV1.z,rV1.w};
    #pragma unroll
    for (int t=0;t<4;t++){
      Vh[(vd0+t)*72 + vkey0] = (u16)(v0[t]&0xFFFFu);
      Vl[(vd0+t)*72 + vkey0] = (u16)(v0[t]>>16);
      Vh[(vd1+t)*72 + vkey1] = (u16)(v1[t]&0xFFFFu);
      Vl[(vd1+t)*72 + vkey1] = (u16)(v1[t]>>16);
    }
  };

  const f32x4 z4 = {0.f,0.f,0.f,0.f};
  f32x4 oacc0 = z4, oacc1 = z4;
  float lp[4] = {0.f,0.f,0.f,0.f};

  load_kv(kt0);
  for (int kt = kt0; kt < kt1; kt++){
    write_kv();
    __syncthreads();
    if (kt + 1 < kt1) load_kv(kt + 1);

    #pragma unroll
    for (int s16t=0; s16t<4; s16t++){
      s16x8 kbh = *(const s16x8*)&Kh[(s16t*16 + lr)*40 + lh*8];
      s16x8 kbl = *(const s16x8*)&Kl[(s16t*16 + lr)*40 + lh*8];
      f32x4 a = z4;
      a = __builtin_amdgcn_mfma_f32_16x16x32_bf16(qh, kbh, a, 0,0,0);
      a = __builtin_amdgcn_mfma_f32_16x16x32_bf16(qh, kbl, a, 0,0,0);
      a = __builtin_amdgcn_mfma_f32_16x16x32_bf16(ql, kbh, a, 0,0,0);
      #pragma unroll
      for (int r=0;r<4;r++){
        float p = __expf(a[r]*scale);     // no max-shift: scores bounded
        lp[r] += p;
        u16 hh,ll; splitf(p,hh,ll);
        int off = (lh*4 + r)*72 + s16t*16 + lr;
        Ph[wv][off] = hh;
        Pl[wv][off] = ll;
      }
    }
    #pragma unroll
    for (int ks=0; ks<2; ks++){
      s16x8 pah = *(const s16x8*)&Ph[wv][lr*72 + ks*32 + lh*8];
      s16x8 pal = *(const s16x8*)&Pl[wv][lr*72 + ks*32 + lh*8];
      s16x8 vh0 = *(const s16x8*)&Vh[lr*72      + ks*32 + lh*8];
      s16x8 vl0 = *(const s16x8*)&Vl[lr*72      + ks*32 + lh*8];
      s16x8 vh1 = *(const s16x8*)&Vh[(16+lr)*72 + ks*32 + lh*8];
      s16x8 vl1 = *(const s16x8*)&Vl[(16+lr)*72 + ks*32 + lh*8];
      oacc0 = __builtin_amdgcn_mfma_f32_16x16x32_bf16(pah, vh0, oacc0, 0,0,0);
      oacc0 = __builtin_amdgcn_mfma_f32_16x16x32_bf16(pah, vl0, oacc0, 0,0,0);
      oacc0 = __builtin_amdgcn_mfma_f32_16x16x32_bf16(pal, vh0, oacc0, 0,0,0);
      oacc1 = __builtin_amdgcn_mfma_f32_16x16x32_bf16(pah, vh1, oacc1, 0,0,0);
      oacc1 = __builtin_amdgcn_mfma_f32_16x16x32_bf16(pah, vl1, oacc1, 0,0,0);
      oacc1 = __builtin_amdgcn_mfma_f32_16x16x32_bf16(pal, vh1, oacc1, 0,0,0);
    }
    __syncthreads();
  }
  #pragma unroll
  for (int mask=1; mask<=8; mask<<=1){
    #pragma unroll
    for (int r=0;r<4;r++) lp[r] += __shfl_xor(lp[r], mask);
  }
  #pragma unroll
  for (int r=0;r<4;r++){
    int q = qt*64 + wv*16 + lh*4 + r;
    long n = (long)q*NB + b;
    long orow = n*DM + h*32;
    Op[orow + lr]      = oacc0[r];
    Op[orow + 16 + lr] = oacc1[r];
    if (lr == 0) lArr[n*8 + h] = lp[r];
  }
}

// ---------------- LN / gate helpers ----------------
__device__ __forceinline__ float wave_sum(float v){
  #pragma unroll
  for (int m=1; m<64; m<<=1) v += __shfl_xor(v, m);
  return v;
}

__device__ __forceinline__ float4 ln_finish(float4 a, const float* g, const float* beta, int lane){
  float sum = wave_sum(a.x+a.y+a.z+a.w);
  float sq  = wave_sum(a.x*a.x + a.y*a.y + a.z*a.z + a.w*a.w);
  float mean = sum * (1.f/DM);
  float var  = sq * (1.f/DM) - mean*mean;
  float inv = 1.0f / sqrtf(var + 1e-5f);
  float4 gg = ld4(&g[lane*4]);
  float4 bb = ld4(&beta[lane*4]);
  float4 ov;
  ov.x = (a.x-mean)*inv*gg.x + bb.x;
  ov.y = (a.y-mean)*inv*gg.y + bb.y;
  ov.z = (a.z-mean)*inv*gg.z + bb.z;
  ov.w = (a.w-mean)*inv*gg.w + bb.w;
  return ov;
}

__device__ __forceinline__ void gate_from_regs(float4 ov, int row, int lane,
    const float* GW, const float* GB, float* scores, int* topi){
  float lg[8];
  #pragma unroll
  for (int e=0; e<8; e++){
    float4 wv = ld4(&GW[e*DM + lane*4]);
    lg[e] = ov.x*wv.x + ov.y*wv.y + ov.z*wv.z + ov.w*wv.w;
  }
  #pragma unroll
  for (int mask=1; mask<64; mask<<=1){
    #pragma unroll
    for (int e=0; e<8; e++) lg[e] += __shfl_xor(lg[e], mask);
  }
  #pragma unroll
  for (int e=0; e<8; e++) lg[e] += GB[e];
  int i0 = 0; float v0 = lg[0];
  #pragma unroll
  for (int e=1; e<8; e++) if (lg[e] > v0){ v0 = lg[e]; i0 = e; }
  int i1 = -1; float v1 = -1e30f;
  #pragma unroll
  for (int e=0; e<8; e++) if (e != i0 && lg[e] > v1){ v1 = lg[e]; i1 = e; }
  if (lane == 0){
    float ee = expf(v1 - v0);
    float inv = 1.f/(1.f + ee);
    scores[row*2]   = inv;
    scores[row*2+1] = ee*inv;
    topi[row*2]   = i0;
    topi[row*2+1] = i1;
  }
}

__global__ __launch_bounds__(256) void add_ln_le(const float* __restrict__ A,
    const float* __restrict__ Bv, const float* __restrict__ g, const float* __restrict__ beta,
    float* __restrict__ out)
{
  int row = blockIdx.x*4 + (threadIdx.x >> 6);
  int lane = threadIdx.x & 63;
  float4 a = ld4(&A[(long)(row>>2)*DM + lane*4]);
  float4 b = ld4(&Bv[(long)row*DM + lane*4]);
  a.x+=b.x; a.y+=b.y; a.z+=b.z; a.w+=b.w;
  float4 ov = ln_finish(a, g, beta, lane);
  st4(&out[(long)row*DM + lane*4], ov);
}

__global__ __launch_bounds__(256) void add_ln_gate(const float* __restrict__ A,
    const float* __restrict__ Bv, const float* __restrict__ g, const float* __restrict__ beta,
    float* __restrict__ out, const float* __restrict__ GW, const float* __restrict__ GB,
    float* __restrict__ scores, int* __restrict__ topi)
{
  int row = blockIdx.x*4 + (threadIdx.x >> 6);
  int lane = threadIdx.x & 63;
  float4 a = ld4(&A[(long)row*DM + lane*4]);
  float4 b = ld4(&Bv[(long)row*DM + lane*4]);
  a.x+=b.x; a.y+=b.y; a.z+=b.z; a.w+=b.w;
  float4 ov = ln_finish(a, g, beta, lane);
  st4(&out[(long)row*DM + lane*4], ov);
  gate_from_regs(ov, row, lane, GW, GB, scores, topi);
}

__global__ __launch_bounds__(256) void moe_ln_gate_k(const float* __restrict__ base,
    const float* __restrict__ yt,
    const float* __restrict__ g, const float* __restrict__ beta, float* __restrict__ out,
    const float* __restrict__ GW, const float* __restrict__ GB,
    float* __restrict__ scores2, int* __restrict__ topi2)
{
  int row = blockIdx.x*4 + (threadIdx.x >> 6);
  int lane = threadIdx.x & 63;
  float4 a  = ld4(&base[(long)row*DM + lane*4]);
  float4 y0 = ld4(&yt[(long)(row*2)*DM + lane*4]);
  float4 y1 = ld4(&yt[(long)(row*2+1)*DM + lane*4]);
  a.x += y0.x + y1.x;
  a.y += y0.y + y1.y;
  a.z += y0.z + y1.z;
  a.w += y0.w + y1.w;
  float4 ov = ln_finish(a, g, beta, lane);
  st4(&out[(long)row*DM + lane*4], ov);
  gate_from_regs(ov, row, lane, GW, GB, scores2, topi2);
}

__global__ __launch_bounds__(256) void moe_ln_fin_k(const float* __restrict__ base,
    const float* __restrict__ yt,
    const float* __restrict__ g, const float* __restrict__ beta, float* __restrict__ out)
{
  int row = blockIdx.x*4 + (threadIdx.x >> 6);
  int lane = threadIdx.x & 63;
  float4 a  = ld4(&base[(long)row*DM + lane*4]);
  float4 y0 = ld4(&yt[(long)(row*2)*DM + lane*4]);
  float4 y1 = ld4(&yt[(long)(row*2+1)*DM + lane*4]);
  a.x += y0.x + y1.x;
  a.y += y0.y + y1.y;
  a.z += y0.z + y1.z;
  a.w += y0.w + y1.w;
  float4 ov = ln_finish(a, g, beta, lane);
  st4(&out[(long)row*DM + lane*4], ov);
}

__global__ void offs_assign(const int* __restrict__ topi, int* __restrict__ cnt_g,
    int* __restrict__ offs_g, int* __restrict__ map, int* __restrict__ jmap)
{
  __shared__ int hist[72];
  __shared__ int offs[8];
  __shared__ int c2[8];
  int tid = threadIdx.x;
  if (tid < 72) hist[tid] = 0;
  __syncthreads();
  for (int idx = tid; idx < 2*NTOK; idx += 256){
    int e = topi[idx];
    atomicAdd(&hist[e*9 + (tid & 7)], 1);
  }
  __syncthreads();
  if (tid == 0){
    int o = 0;
    #pragma unroll
    for (int e=0; e<8; e++){
      int c = 0;
      #pragma unroll
      for (int s=0; s<8; s++) c += hist[e*9 + s];
      cnt_g[e] = c;
      offs[e] = o;
      offs_g[e] = o;
      o += c;
      c2[e] = 0;
    }
  }
  __syncthreads();
  for (int n = tid; n < NTOK; n += 256){
    #pragma unroll
    for (int j=0; j<2; j++){
      int e = topi[n*2+j];
      int slot = atomicAdd(&c2[e], 1);
      int r = offs[e] + slot;
      map[r] = n;
      jmap[r] = n*2 + j;
    }
  }
}

// =================================================================
extern "C" void kernel_launch(void* const* d_in, const int* in_sizes, int n_in,
                              void* d_out, int out_size, void* d_ws, size_t ws_size,
                              hipStream_t stream)
{
  const float* x      = (const float*)d_in[0];
  const float* Wi     = (const float*)d_in[1];
  const float* bi     = (const float*)d_in[2];
  const float* le     = (const float*)d_in[3];
  const float* Wqkv_s = (const float*)d_in[4];
  const float* bqkv_s = (const float*)d_in[5];
  const float* Wo_s   = (const float*)d_in[6];
  const float* bo_s   = (const float*)d_in[7];
  const float* Wqkv_c = (const float*)d_in[8];
  const float* bqkv_c = (const float*)d_in[9];
  const float* Wo_c   = (const float*)d_in[10];
  const float* bo_c   = (const float*)d_in[11];
  const float* ln_g   = (const float*)d_in[12];
  const float* ln_b   = (const float*)d_in[13];
  const float* gw1    = (const float*)d_in[14];
  const float* gb1    = (const float*)d_in[15];
  const float* W1a    = (const float*)d_in[16];
  const float* b1a    = (const float*)d_in[17];
  const float* W2a    = (const float*)d_in[18];
  const float* b2a    = (const float*)d_in[19];
  const float* gw2    = (const float*)d_in[20];
  const float* gb2    = (const float*)d_in[21];
  const float* W1b    = (const float*)d_in[22];
  const float* b1b    = (const float*)d_in[23];
  const float* W2b    = (const float*)d_in[24];
  const float* b2b    = (const float*)d_in[25];
  const float* Wout   = (const float*)d_in[26];
  const float* bout   = (const float*)d_in[27];

  float* w = (float*)d_ws;
  const long SZ = 1048576;            // NTOK*DM
  float* pos  = w;                    // 262144
  float* src  = pos  + 262144;
  float* t2s  = src  + SZ;
  float* tgtA = t2s  + SZ;
  float* dec  = tgtA + SZ;
  float* od   = dec;                  // ALIAS: od and dec have disjoint live ranges
  float* od2  = dec  + SZ;
  float* yt   = od2  + SZ;            // 2,097,152 fp32
  float* scoresA = yt + 2097152;      // 8192
  float* scoresB = scoresA + 8192;    // 8192
  u16* wsp  = (u16*)(scoresB + 8192);
  u16* W1ah = wsp;             u16* W1al = wsp + 2097152;
  u16* W1bh = wsp + 4194304;   u16* W1bl = wsp + 6291456;
  u16* W2ah = wsp + 8388608;   u16* W2al = wsp + 10485760;
  u16* W2bh = wsp + 12582912;  u16* W2bl = wsp + 14680064;
  u16* dwp  = wsp + 16777216;
  u16* Wih   = dwp;            u16* Wil   = dwp + 69632;
  u16* Wqsh  = dwp + 139264;   u16* Wqsl  = dwp + 335872;
  u16* Wosh  = dwp + 532480;   u16* Wosl  = dwp + 598016;
  u16* Wqch  = dwp + 663552;   u16* Wqcl  = dwp + 860160;
  u16* Woch  = dwp + 1056768;  u16* Wocl  = dwp + 1122304;
  u16* Wouth = dwp + 1187840;  u16* Woutl = dwp + 1257472;
  // overlay region R: 8,388,608 floats
  float* R   = (float*)(dwp + 1327104);
  float* tok = R;                     // dead before q written
  u32*  q    = (u32*)R;               // packed pairs
  u32*  k    = (u32*)(R + SZ);        // packed; reused as t2c (fp32) after attn
  u32*  v    = (u32*)(R + 2*SZ);      // packed pairs
  float* OpB = R + 4*SZ;              // split-KV partial O: 2 x SZ fp32
  float* lB  = R + 6*SZ;              // l halves: 2 x 65536
  u32*  hg   = (u32*)R;               // MoE phase (q..Op dead)
  float* rec = R;                     // final
  int* ip    = (int*)(R + 8388608);
  int* topiA = ip;
  int* topiB = ip + 8192;
  int* map   = ip + 16384;
  int* jmapA = ip + 24576;
  int* jmapB = ip + 32768;
  int* cnts  = ip + 40960;
  int* offsg = ip + 40992;

  dim3 blk(256);
  dim3 gDense(4, 128, 1);
  dim3 gQKV(4, 128, 3);
  dim3 gMoe1(16, 128, 8);
  dim3 gMoe2(4, 128, 8);
  dim3 gAttn(16, 32, 2);

  pos_kernel<<<NHW, DM, 0, stream>>>(pos);
  tin_kernel<<<(NTOK*NCIN + 255)/256, blk, 0, stream>>>(x, tok);

  // weight prep: 3 launches instead of 10
  tconv2_kernel<<<dim3(32, 8, 16), blk, 0, stream>>>(W1a, W1ah, W1al, W1b, W1bh, W1bl, DM, NDFF);
  tconv2_kernel<<<dim3(8, 32, 16), blk, 0, stream>>>(W2a, W2ah, W2al, W2b, W2bh, W2bl, NDFF, DM);
  wsplit6_kernel<<<dim3(768, 1, 6), blk, 0, stream>>>(
      Wi,     Wih,   Wil,   69632,
      Wqkv_s, Wqsh,  Wqsl,  196608,
      Wo_s,   Wosh,  Wosl,  65536,
      Wqkv_c, Wqch,  Wqcl,  196608,
      Wo_c,   Woch,  Wocl,  65536,
      Wout,   Wouth, Woutl, 69632);

  gemm_in<<<gDense, blk, GEMM_SMEM32, stream>>>(tok, Wih, Wil, bi, src);

  gemm_qkv_s<<<gQKV, blk, GEMM_SMEM32, stream>>>(le, src, src, pos, Wqsh, Wqsl, bqkv_s, q, k, v);
  attn_mfma<<<gAttn, blk, 0, stream>>>(q, k, v, OpB, lB);
  gemm_wos<<<gDense, blk, GEMM_SMEM32, stream>>>(OpB, lB, Wosh, Wosl, bo_s, t2s);

  const float* decIn = src;
  for (int i = 0; i < 2; i++){
    int* cntA = cnts + (i*2)*8;   int* offsA = offsg + (i*2)*8;
    int* cntB = cnts + (i*2+1)*8; int* offsB = offsg + (i*2+1)*8;

    add_ln_le<<<1024, blk, 0, stream>>>(le, t2s, ln_g + (4*i)*DM, ln_b + (4*i)*DM, tgtA);
    gemm_qkv_c<<<gQKV, blk, GEMM_SMEM32, stream>>>(tgtA, decIn, decIn, pos, Wqch, Wqcl, bqkv_c, q, k, v);
    attn_mfma<<<gAttn, blk, 0, stream>>>(q, k, v, OpB, lB);
    gemm_woc<<<gDense, blk, GEMM_SMEM32, stream>>>(OpB, lB, Woch, Wocl, bo_c, (float*)k);
    add_ln_gate<<<1024, blk, 0, stream>>>(tgtA, (float*)k, ln_g + (4*i+1)*DM, ln_b + (4*i+1)*DM, od,
        gw1, gb1, scoresA, topiA);

    offs_assign<<<1, blk, 0, stream>>>(topiA, cntA, offsA, map, jmapA);
    gemm_m1<<<gMoe1, blk, GEMM_SMEM32, stream>>>(od, W1ah, W1al, b1a, hg, map, cntA, offsA);
    gemm_m2<<<gMoe2, blk, GEMM_SMEM64, stream>>>(hg, W2ah, W2al, b2a, yt, cntA, offsA,
        jmapA, scoresA);
    moe_ln_gate_k<<<1024, blk, 0, stream>>>(od, yt,
        ln_g + (4*i+2)*DM, ln_b + (4*i+2)*DM, od2, gw2, gb2, scoresB, topiB);

    offs_assign<<<1, blk, 0, stream>>>(topiB, cntB, offsB, map, jmapB);
    gemm_m1<<<gMoe1, blk, GEMM_SMEM32, stream>>>(od2, W1bh, W1bl, b1b, hg, map, cntB, offsB);
    gemm_m2<<<gMoe2, blk, GEMM_SMEM64, stream>>>(hg, W2bh, W2bl, b2b, yt, cntB, offsB,
        jmapB, scoresB);
    moe_ln_fin_k<<<1024, blk, 0, stream>>>(od2, yt,
        ln_g + (4*i+3)*DM, ln_b + (4*i+3)*DM, dec);

    decIn = dec;
  }

  gemm_out_k<<<dim3(5,128,1), blk, GEMM_SMEM32, stream>>>(dec, Wouth, Woutl, bout, rec);
  tout_kernel<<<(NTOK*NCIN + 255)/256, blk, 0, stream>>>(rec, (float*)d_out);
}